// Round 9
// baseline (179.755 us; speedup 1.0000x reference)
//
#include <hip/hip_runtime.h>
#include <hip/hip_bf16.h>
#include <math.h>

#define B_ 2
#define N_ 2048
#define C_ 1024
#define H_ 16
#define G_ 4
#define D_ 64
#define QKV_N 1152   // 1024 q + 64 ksum + 64 vsum

#define QSCALE 0.18033688011112042f   // 0.125 * log2(e)

using short8  = __attribute__((ext_vector_type(8))) short;
using short4v = __attribute__((ext_vector_type(4))) short;
using float4v = __attribute__((ext_vector_type(4))) float;

#if __has_builtin(__builtin_amdgcn_mfma_f32_16x16x16_bf16)
#define MFMA16K16(A, B, C) __builtin_amdgcn_mfma_f32_16x16x16_bf16(A, B, C, 0, 0, 0)
#else
#define MFMA16K16(A, B, C) __builtin_amdgcn_mfma_f32_16x16x16bf16_1k(A, B, C, 0, 0, 0)
#endif

__device__ __forceinline__ ushort f2bf(float f) {
    union { float f; unsigned u; } v; v.f = f;
    unsigned r = (v.u + 0x7FFF + ((v.u >> 16) & 1)) >> 16;  // RNE
    return (ushort)r;
}
__device__ __forceinline__ float bf2f(ushort u) {
    union { unsigned u; float f; } t; t.u = ((unsigned)u) << 16; return t.f;
}
__device__ __forceinline__ unsigned pack_bf16(float a, float b) {
#if __has_builtin(__builtin_amdgcn_cvt_pk_bf16_f32)
    auto t = __builtin_amdgcn_cvt_pk_bf16_f32(a, b);
    unsigned r; __builtin_memcpy(&r, &t, 4); return r;
#else
    return (unsigned)f2bf(a) | ((unsigned)f2bf(b) << 16);
#endif
}
__device__ __forceinline__ float fexp2(float x) {
#if __has_builtin(__builtin_amdgcn_exp2f)
    return __builtin_amdgcn_exp2f(x);
#else
    return exp2f(x);
#endif
}

// ---------------------------------------------------------------------------
// Fused prep (one launch):
//   blocks [0,4096)     : x fp32 -> bf16
//   [4096,4352)         : w_q^T   -> wqkvT rows 0..1023
//   [4352,4608)         : w_out^T -> woutT
//   [4608,4624)         : kv weight g-sum + transpose -> wqkvT rows 1024..1151
// ---------------------------------------------------------------------------
__device__ void tconv_body(const float* __restrict__ src, ushort* __restrict__ dst,
                           int K, int N, int bx, int by, float (*T)[65]) {
    const int n0 = bx * 64, k0 = by * 64;
    const int tid = threadIdx.x;
    #pragma unroll
    for (int s = 0; s < 16; ++s) {
        int idx = tid + s * 256; int r = idx >> 6, cc = idx & 63;
        T[r][cc] = src[(size_t)(k0 + r) * N + n0 + cc];
    }
    __syncthreads();
    #pragma unroll
    for (int s = 0; s < 16; ++s) {
        int idx = tid + s * 256; int r = idx >> 6, cc = idx & 63;
        dst[(size_t)(n0 + r) * K + k0 + cc] = f2bf(T[cc][r]);
    }
}

__global__ void prep(const float* __restrict__ x, const float* __restrict__ w_q,
                     const float* __restrict__ w_kv, const float* __restrict__ w_out,
                     ushort* __restrict__ xb, ushort* __restrict__ wqkvT,
                     ushort* __restrict__ woutT) {
    __shared__ float T[64][65];
    const int blk = blockIdx.x, tid = threadIdx.x;
    if (blk < 4096) {
        int i = blk * 1024 + tid * 4;
        float4 v = *(const float4*)(x + i);
        ushort4 o;
        o.x = f2bf(v.x); o.y = f2bf(v.y); o.z = f2bf(v.z); o.w = f2bf(v.w);
        *(ushort4*)(xb + i) = o;
    } else if (blk < 4352) {
        int idx = blk - 4096;
        tconv_body(w_q, wqkvT, C_, C_, idx & 15, idx >> 4, T);
    } else if (blk < 4608) {
        int idx = blk - 4352;
        tconv_body(w_out, woutT, C_, C_, idx & 15, idx >> 4, T);
    } else {
        // kv g-sum + transpose: wqkvT[1024+d][k] = sum_g w_kv[k][g*64+d],
        //                       wqkvT[1088+d][k] = sum_g w_kv[k][256+g*64+d]
        const int k0 = (blk - 4608) * 64;
        #pragma unroll
        for (int it = 0; it < 4; ++it) {
            int p = tid + it * 256;              // 1024 (kk, d-quad) pairs
            int kk = p >> 4, d4 = (p & 15) * 4;
            float ks[4] = {0, 0, 0, 0}, vs[4] = {0, 0, 0, 0};
            #pragma unroll
            for (int g = 0; g < G_; ++g) {
                float4 a = *(const float4*)(w_kv + (size_t)(k0 + kk) * 512 + g * 64 + d4);
                float4 b = *(const float4*)(w_kv + (size_t)(k0 + kk) * 512 + 256 + g * 64 + d4);
                ks[0] += a.x; ks[1] += a.y; ks[2] += a.z; ks[3] += a.w;
                vs[0] += b.x; vs[1] += b.y; vs[2] += b.z; vs[3] += b.w;
            }
            #pragma unroll
            for (int e = 0; e < 4; ++e) {
                wqkvT[(size_t)(1024 + d4 + e) * C_ + k0 + kk] = f2bf(ks[e]);
                wqkvT[(size_t)(1088 + d4 + e) * C_ + k0 + kk] = f2bf(vs[e]);
            }
        }
    }
}

// ---------------------------------------------------------------------------
// bf16 MFMA GEMM, 128x64 tile, BK=64, double-buffered LDS, 2-phase prefetch.
// Global-side XOR chunk swizzle; 4 waves x acc[2][4].
// MODE 1 (qkv): bx<16  -> fused rope+QSCALE on Q  -> qkvb (bf16, std index).
//               bx==16 -> fused rope on Ksum      -> Kt[row][d].
//               bx==17 -> Vsum transpose          -> VtT[d][row].
//   All three use the R4-verified pairing: partner d^32 = acc[m][nn^2][r]
//   in the SAME thread (bit5 of column offset == bit1 of nn).
// MODE 2 (out): f32 C write.   [R6 config — best measured total 175.4]
// ---------------------------------------------------------------------------
template <int MODE>
__global__ __launch_bounds__(256) void gemm128p(const ushort* __restrict__ A,
                                                const ushort* __restrict__ Bt,
                                                void* __restrict__ Cv,
                                                ushort* __restrict__ Kt,
                                                ushort* __restrict__ VtT,
                                                int M, int N, int K) {
    __shared__ __align__(16) ushort As[2][128 * 64];
    __shared__ __align__(16) ushort Bs[2][64 * 64];

    const int tid = threadIdx.x, wave = tid >> 6, lane = tid & 63;
    const int g = lane >> 4, c = lane & 15;
    const int m0 = blockIdx.y * 128, n0 = blockIdx.x * 64;

    const int lr = tid >> 3;                 // row within 32-row slab
    const int lq = tid & 7;                  // 16B-chunk slot within row
    const int gsw = (lq ^ (lr & 7)) * 8;     // global-side XOR chunk swizzle
    const ushort* pa = A  + (size_t)(m0 + lr) * K + gsw;
    const ushort* pb = Bt + (size_t)(n0 + lr) * K + gsw;

    auto stage = [&](int buf, int k0) {
        #pragma unroll
        for (int i = 0; i < 4; ++i)
            __builtin_amdgcn_global_load_lds(
                (const __attribute__((address_space(1))) void*)(pa + (size_t)i * 32 * K + k0),
                (__attribute__((address_space(3))) void*)&As[buf][(i * 32 + wave * 8) * 64], 16, 0, 0);
        #pragma unroll
        for (int i = 0; i < 2; ++i)
            __builtin_amdgcn_global_load_lds(
                (const __attribute__((address_space(1))) void*)(pb + (size_t)i * 32 * K + k0),
                (__attribute__((address_space(3))) void*)&Bs[buf][(i * 32 + wave * 8) * 64], 16, 0, 0);
    };

    float4v acc[2][4];
    #pragma unroll
    for (int m = 0; m < 2; ++m)
        #pragma unroll
        for (int n = 0; n < 4; ++n) acc[m][n] = {0, 0, 0, 0};

    stage(0, 0);
    __syncthreads();

    const int NT = K >> 6;
    int cur = 0;
    for (int t = 0; t < NT; ++t) {
        if (t + 1 < NT) stage(cur ^ 1, (t + 1) << 6);

        #pragma unroll
        for (int kk = 0; kk < 2; ++kk) {
            const int c7 = c & 7;
            short8 af[2], bf[4];
            #pragma unroll
            for (int m = 0; m < 2; ++m)
                af[m] = *(const short8*)&As[cur][(wave * 32 + m * 16 + c) * 64 + ((kk * 4 + g) ^ c7) * 8];
            #pragma unroll
            for (int n = 0; n < 4; ++n)
                bf[n] = *(const short8*)&Bs[cur][(n * 16 + c) * 64 + ((kk * 4 + g) ^ c7) * 8];
            #pragma unroll
            for (int m = 0; m < 2; ++m)
                #pragma unroll
                for (int n = 0; n < 4; ++n)
                    acc[m][n] = __builtin_amdgcn_mfma_f32_16x16x32_bf16(af[m], bf[n], acc[m][n], 0, 0, 0);
        }
        __syncthreads();   // drains vmcnt(0): next buffer's loads landed
        cur ^= 1;
    }

    if (MODE == 1) {
        if (blockIdx.x < 16) {
            // fused rope + QSCALE on Q: qkvb[rowi][bx*64 + d], d = nn*16+c
            const float invf_e = __powf(10000.0f, -(float)c * (1.0f / 32.0f));
            const float invf_o = __powf(10000.0f, -(float)(c + 16) * (1.0f / 32.0f));
            #pragma unroll
            for (int m = 0; m < 2; ++m)
                #pragma unroll
                for (int r = 0; r < 4; ++r) {
                    const int rowi = m0 + wave * 32 + m * 16 + 4 * g + r;
                    const float nf = (float)(rowi & (N_ - 1));
                    float sn0, cs0, sn1, cs1;
                    __sincosf(nf * invf_e, &sn0, &cs0);
                    __sincosf(nf * invf_o, &sn1, &cs1);
                    #pragma unroll
                    for (int nn = 0; nn < 4; ++nn) {
                        const float v = acc[m][nn][r], p = acc[m][nn ^ 2][r];
                        const float rh = (nn < 2) ? -p : p;
                        const float sn = (nn & 1) ? sn1 : sn0;
                        const float cs = (nn & 1) ? cs1 : cs0;
                        ((ushort*)Cv)[(size_t)rowi * N + n0 + nn * 16 + c] =
                            f2bf((v * cs + rh * sn) * QSCALE);
                    }
                }
            return;
        }
        if (blockIdx.x == 16) {
            // fused rope on Ksum: Kt[rowi][d] = k*cos + rot_half(k)*sin
            const float invf_e = __powf(10000.0f, -(float)c * (1.0f / 32.0f));
            const float invf_o = __powf(10000.0f, -(float)(c + 16) * (1.0f / 32.0f));
            #pragma unroll
            for (int m = 0; m < 2; ++m)
                #pragma unroll
                for (int r = 0; r < 4; ++r) {
                    const int rowi = m0 + wave * 32 + m * 16 + 4 * g + r;
                    const float nf = (float)(rowi & (N_ - 1));
                    float sn0, cs0, sn1, cs1;
                    __sincosf(nf * invf_e, &sn0, &cs0);
                    __sincosf(nf * invf_o, &sn1, &cs1);
                    #pragma unroll
                    for (int nn = 0; nn < 4; ++nn) {
                        const float v = acc[m][nn][r], p = acc[m][nn ^ 2][r];
                        const float rh = (nn < 2) ? -p : p;
                        const float sn = (nn & 1) ? sn1 : sn0;
                        const float cs = (nn & 1) ? cs1 : cs0;
                        Kt[(size_t)rowi * 64 + nn * 16 + c] = f2bf(v * cs + rh * sn);
                    }
                }
        } else {
            // Vsum transpose: VtT[b][d][n]
            #pragma unroll
            for (int m = 0; m < 2; ++m)
                #pragma unroll
                for (int nn = 0; nn < 4; ++nn)
                    #pragma unroll
                    for (int r = 0; r < 4; ++r) {
                        const int rowi = m0 + wave * 32 + m * 16 + 4 * g + r;
                        const int n = rowi & (N_ - 1), bb = rowi >> 11;
                        VtT[((size_t)bb * 64 + nn * 16 + c) * N_ + n] = f2bf(acc[m][nn][r]);
                    }
        }
        return;
    }

    #pragma unroll
    for (int m = 0; m < 2; ++m)
        #pragma unroll
        for (int n = 0; n < 4; ++n)
            #pragma unroll
            for (int r = 0; r < 4; ++r) {
                int rowi = m0 + wave * 32 + m * 16 + 4 * g + r;
                int coli = n0 + n * 16 + c;
                ((float*)Cv)[(size_t)rowi * N + coli] = acc[m][n][r];
            }
}

// ---------------------------------------------------------------------------
// Flash attention v16 = attn14's math with 512-THREAD blocks (8 waves).
// Occupancy fix that holds staging-per-score and VGPR constant:
//   - grid stays 512 (K-split x2, 2 blocks/CU, tail-free)
//   - each wave owns 32 Q-rows (o[2][4], qf[2][2] -> VGPR ~90, fits 4/SIMD)
//   - waves/SIMD: 2 -> 4 (total waves 2048 -> 4096)
//   - one 16KB K/V tile now serves 8 waves; each wave stages 8 rows of K
//     and 8 of V (1 load + 1 ds_write each) -- total staging unchanged
//   - cost: kf/vf ds_reads amortize over a<2 instead of a<4 (x2 LDS reads;
//     separate pipe, hidden by the doubled TLP)
// (R1 failed this via per-block Q-split [staging x2 + spill]; R7 via VGPR 192.)
// ---------------------------------------------------------------------------
__global__ __launch_bounds__(512) void attn16(
        const ushort* __restrict__ qkvb, const ushort* __restrict__ Kt,
        const ushort* __restrict__ VtT,
        ushort* __restrict__ oP0, ushort* __restrict__ oP1,
        float* __restrict__ lP0, float* __restrict__ lP1) {
    const int s  = blockIdx.x & 1;
    const int qt = (blockIdx.x >> 1) & 7;
    const int h  = (blockIdx.x >> 4) & 15;
    const int b  = blockIdx.x >> 8;
    const int tid = threadIdx.x, wave = tid >> 6, lane = tid & 63;
    const int g = lane >> 4, c = lane & 15;

    __shared__ __align__(16) ushort Ksh[64 * 64];   // [j-local][d], XOR-swizzled
    __shared__ __align__(16) ushort Vsh[64 * 64];   // [d][j-local], XOR-swizzled

    ushort* oPs = s ? oP1 : oP0;
    float*  lPs = s ? lP1 : lP0;

    const int i0 = qt * 256 + wave * 32;

    short8 qf[2][2];
    #pragma unroll
    for (int a = 0; a < 2; ++a) {
        const int row = i0 + a * 16 + c;
        const ushort* qrow = qkvb + (size_t)(b * N_ + row) * QKV_N + h * 64;
        qf[a][0] = *(const short8*)(qrow + 8 * g);
        qf[a][1] = *(const short8*)(qrow + 32 + 8 * g);
    }

    float4v o[2][4];
    #pragma unroll
    for (int a = 0; a < 2; ++a)
        #pragma unroll
        for (int f = 0; f < 4; ++f) o[a][f] = {0, 0, 0, 0};
    float ll[2] = {0.f, 0.f};

    const ushort* Kb = Kt  + (size_t)b * N_ * 64;
    const ushort* Vb = VtT + (size_t)b * 64 * N_;
    const int lr8 = lane >> 3, lq8 = lane & 7;
    const int wpos = (lq8 ^ lr8) * 8;
    const int j0 = s * (N_ / 2);
    const int NT = (N_ / 2) / 64;

    // each wave stages 8 rows of K ([j][d]) and 8 rows of V ([d][j])
    short8 kr0 = *(const short8*)(Kb + (size_t)(j0 + wave * 8 + lr8) * 64 + lq8 * 8);
    short8 vr0 = *(const short8*)(Vb + (size_t)(wave * 8 + lr8) * N_ + j0 + lq8 * 8);

    for (int t = 0; t < NT; ++t) {
        __syncthreads();
        *(short8*)&Ksh[(wave * 8 + lr8) * 64 + wpos] = kr0;
        *(short8*)&Vsh[(wave * 8 + lr8) * 64 + wpos] = vr0;
        __syncthreads();
        if (t + 1 < NT) {
            const int jn = j0 + (t + 1) * 64;
            kr0 = *(const short8*)(Kb + (size_t)(jn + wave * 8 + lr8) * 64 + lq8 * 8);
            vr0 = *(const short8*)(Vb + (size_t)(wave * 8 + lr8) * N_ + jn + lq8 * 8);
        }

        #pragma unroll
        for (int jt4 = 0; jt4 < 4; ++jt4) {
            const int R = jt4 * 16 + c;
            short8 kf0 = *(const short8*)&Ksh[R * 64 + ((g ^ (c & 7)) * 8)];
            short8 kf1 = *(const short8*)&Ksh[R * 64 + (((g ^ 4) ^ (c & 7)) * 8)];
            short4v vf[4];
            #pragma unroll
            for (int f = 0; f < 4; ++f)
                vf[f] = *(const short4v*)&Vsh[(16 * f + c) * 64 +
                          (((jt4 * 2 + (g >> 1)) ^ (c & 7)) * 8) + (g & 1) * 4];

            #pragma unroll
            for (int a = 0; a < 2; ++a) {
                float4v st = {0, 0, 0, 0};
                st = __builtin_amdgcn_mfma_f32_16x16x32_bf16(kf0, qf[a][0], st, 0, 0, 0);
                st = __builtin_amdgcn_mfma_f32_16x16x32_bf16(kf1, qf[a][1], st, 0, 0, 0);
                float p0 = fexp2(st[0]), p1 = fexp2(st[1]);
                float p2 = fexp2(st[2]), p3 = fexp2(st[3]);
                ll[a] += (p0 + p1) + (p2 + p3);
                union { unsigned u[2]; short4v v; } pk;
                pk.u[0] = pack_bf16(p0, p1);
                pk.u[1] = pack_bf16(p2, p3);
                #pragma unroll
                for (int f = 0; f < 4; ++f)
                    o[a][f] = MFMA16K16(vf[f], pk.v, o[a][f]);
            }
        }
    }

    #pragma unroll
    for (int a = 0; a < 2; ++a) {
        float lt = ll[a];
        lt += __shfl_xor(lt, 16, 64);
        lt += __shfl_xor(lt, 32, 64);
        const int row = i0 + a * 16 + c;
        if (g == 0) lPs[(size_t)(b * N_ + row) * 16 + h] = lt;
        #pragma unroll
        for (int f = 0; f < 4; ++f) {
            ushort4 w;
            w.x = f2bf(o[a][f][0]); w.y = f2bf(o[a][f][1]);
            w.z = f2bf(o[a][f][2]); w.w = f2bf(o[a][f][3]);
            *(ushort4*)(oPs + (size_t)(b * N_ + row) * 1024 + h * 64 + 16 * f + 4 * g) = w;
        }
    }
}

// ---------------------------------------------------------------------------
// Combine: ao = (oP0 + oP1) / (lP0 + lP1), bf16 out (in-place over oP0 ok)
// ---------------------------------------------------------------------------
__global__ void combine(const ushort* __restrict__ oP0, const ushort* __restrict__ oP1,
                        const float* __restrict__ lP0, const float* __restrict__ lP1,
                        ushort* __restrict__ ao) {
    const int e = (blockIdx.x * 256 + threadIdx.x) * 4;
    const int row = e >> 10, hh = (e >> 6) & 15;
    const float inv = 1.0f / (lP0[row * 16 + hh] + lP1[row * 16 + hh]);
    ushort4 a = *(const ushort4*)(oP0 + e);
    ushort4 b = *(const ushort4*)(oP1 + e);
    ushort4 r;
    r.x = f2bf((bf2f(a.x) + bf2f(b.x)) * inv);
    r.y = f2bf((bf2f(a.y) + bf2f(b.y)) * inv);
    r.z = f2bf((bf2f(a.z) + bf2f(b.z)) * inv);
    r.w = f2bf((bf2f(a.w) + bf2f(b.w)) * inv);
    *(ushort4*)(ao + e) = r;
}

// ---------------------------------------------------------------------------
extern "C" void kernel_launch(void* const* d_in, const int* in_sizes, int n_in,
                              void* d_out, int out_size, void* d_ws, size_t ws_size,
                              hipStream_t stream) {
    const float* x     = (const float*)d_in[0];
    const float* w_q   = (const float*)d_in[1];
    const float* w_kv  = (const float*)d_in[2];
    const float* w_out = (const float*)d_in[3];
    float* out = (float*)d_out;

    const int M = B_ * N_;                               // 4096
    ushort* xb    = (ushort*)d_ws;                       // 4096*1024  (-> oP0 -> ao)
    ushort* wqkvT = xb    + (size_t)M * C_;              // 1152*1024
    ushort* woutT = wqkvT + (size_t)QKV_N * C_;          // 1024*1024
    ushort* qkvb  = woutT + (size_t)C_ * C_;             // 4096*1152
    ushort* Kt    = qkvb  + (size_t)M * QKV_N;           // 2*2048*64
    ushort* VtT   = Kt    + (size_t)B_ * N_ * D_;        // 2*64*2048
    ushort* oP1   = VtT   + (size_t)B_ * D_ * N_;        // 4096*1024 bf16 partial
    float*  lP0   = (float*)(oP1 + (size_t)M * C_);      // 4096*16 fp32
    float*  lP1   = lP0 + (size_t)M * H_;
    ushort* oP0   = xb;   // xb dead after qkv GEMM
    ushort* ao    = xb;   // combine writes in-place over oP0

    prep<<<4624, 256, 0, stream>>>(x, w_q, w_kv, w_out, xb, wqkvT, woutT);
    gemm128p<1><<<dim3(QKV_N / 64, M / 128), 256, 0, stream>>>(xb, wqkvT, qkvb, Kt, VtT, M, QKV_N, C_);
    attn16<<<B_ * H_ * (N_ / 256) * 2, 512, 0, stream>>>(qkvb, Kt, VtT, oP0, oP1, lP0, lP1);
    combine<<<(M * C_) / 1024, 256, 0, stream>>>(oP0, oP1, lP0, lP1, ao);
    gemm128p<2><<<dim3(C_ / 64, M / 128), 256, 0, stream>>>(ao, woutT, out, nullptr, nullptr, M, C_, C_);
}

// Round 10
// 171.952 us; speedup vs baseline: 1.0454x; 1.0454x over previous
//
#include <hip/hip_runtime.h>
#include <hip/hip_bf16.h>
#include <math.h>

#define B_ 2
#define N_ 2048
#define C_ 1024
#define H_ 16
#define G_ 4
#define D_ 64
#define QKV_N 1152   // 1024 q + 64 ksum + 64 vsum

#define QSCALE 0.18033688011112042f   // 0.125 * log2(e)

using short8  = __attribute__((ext_vector_type(8))) short;
using short4v = __attribute__((ext_vector_type(4))) short;
using float4v = __attribute__((ext_vector_type(4))) float;

#if __has_builtin(__builtin_amdgcn_mfma_f32_16x16x16_bf16)
#define MFMA16K16(A, B, C) __builtin_amdgcn_mfma_f32_16x16x16_bf16(A, B, C, 0, 0, 0)
#else
#define MFMA16K16(A, B, C) __builtin_amdgcn_mfma_f32_16x16x16bf16_1k(A, B, C, 0, 0, 0)
#endif

__device__ __forceinline__ ushort f2bf(float f) {
    union { float f; unsigned u; } v; v.f = f;
    unsigned r = (v.u + 0x7FFF + ((v.u >> 16) & 1)) >> 16;  // RNE
    return (ushort)r;
}
__device__ __forceinline__ float bf2f(ushort u) {
    union { unsigned u; float f; } t; t.u = ((unsigned)u) << 16; return t.f;
}
__device__ __forceinline__ unsigned pack_bf16(float a, float b) {
#if __has_builtin(__builtin_amdgcn_cvt_pk_bf16_f32)
    auto t = __builtin_amdgcn_cvt_pk_bf16_f32(a, b);
    unsigned r; __builtin_memcpy(&r, &t, 4); return r;
#else
    return (unsigned)f2bf(a) | ((unsigned)f2bf(b) << 16);
#endif
}
__device__ __forceinline__ float fexp2(float x) {
#if __has_builtin(__builtin_amdgcn_exp2f)
    return __builtin_amdgcn_exp2f(x);
#else
    return exp2f(x);
#endif
}

// ---------------------------------------------------------------------------
// Fused prep (one launch):
//   blocks [0,4096)     : x fp32 -> bf16
//   [4096,4352)         : w_q^T   -> wqkvT rows 0..1023
//   [4352,4608)         : w_out^T -> woutT
//   [4608,4624)         : kv weight g-sum + transpose -> wqkvT rows 1024..1151
// ---------------------------------------------------------------------------
__device__ void tconv_body(const float* __restrict__ src, ushort* __restrict__ dst,
                           int K, int N, int bx, int by, float (*T)[65]) {
    const int n0 = bx * 64, k0 = by * 64;
    const int tid = threadIdx.x;
    #pragma unroll
    for (int s = 0; s < 16; ++s) {
        int idx = tid + s * 256; int r = idx >> 6, cc = idx & 63;
        T[r][cc] = src[(size_t)(k0 + r) * N + n0 + cc];
    }
    __syncthreads();
    #pragma unroll
    for (int s = 0; s < 16; ++s) {
        int idx = tid + s * 256; int r = idx >> 6, cc = idx & 63;
        dst[(size_t)(n0 + r) * K + k0 + cc] = f2bf(T[cc][r]);
    }
}

__global__ void prep(const float* __restrict__ x, const float* __restrict__ w_q,
                     const float* __restrict__ w_kv, const float* __restrict__ w_out,
                     ushort* __restrict__ xb, ushort* __restrict__ wqkvT,
                     ushort* __restrict__ woutT) {
    __shared__ float T[64][65];
    const int blk = blockIdx.x, tid = threadIdx.x;
    if (blk < 4096) {
        int i = blk * 1024 + tid * 4;
        float4 v = *(const float4*)(x + i);
        ushort4 o;
        o.x = f2bf(v.x); o.y = f2bf(v.y); o.z = f2bf(v.z); o.w = f2bf(v.w);
        *(ushort4*)(xb + i) = o;
    } else if (blk < 4352) {
        int idx = blk - 4096;
        tconv_body(w_q, wqkvT, C_, C_, idx & 15, idx >> 4, T);
    } else if (blk < 4608) {
        int idx = blk - 4352;
        tconv_body(w_out, woutT, C_, C_, idx & 15, idx >> 4, T);
    } else {
        // kv g-sum + transpose: wqkvT[1024+d][k] = sum_g w_kv[k][g*64+d],
        //                       wqkvT[1088+d][k] = sum_g w_kv[k][256+g*64+d]
        const int k0 = (blk - 4608) * 64;
        #pragma unroll
        for (int it = 0; it < 4; ++it) {
            int p = tid + it * 256;              // 1024 (kk, d-quad) pairs
            int kk = p >> 4, d4 = (p & 15) * 4;
            float ks[4] = {0, 0, 0, 0}, vs[4] = {0, 0, 0, 0};
            #pragma unroll
            for (int g = 0; g < G_; ++g) {
                float4 a = *(const float4*)(w_kv + (size_t)(k0 + kk) * 512 + g * 64 + d4);
                float4 b = *(const float4*)(w_kv + (size_t)(k0 + kk) * 512 + 256 + g * 64 + d4);
                ks[0] += a.x; ks[1] += a.y; ks[2] += a.z; ks[3] += a.w;
                vs[0] += b.x; vs[1] += b.y; vs[2] += b.z; vs[3] += b.w;
            }
            #pragma unroll
            for (int e = 0; e < 4; ++e) {
                wqkvT[(size_t)(1024 + d4 + e) * C_ + k0 + kk] = f2bf(ks[e]);
                wqkvT[(size_t)(1088 + d4 + e) * C_ + k0 + kk] = f2bf(vs[e]);
            }
        }
    }
}

// ---------------------------------------------------------------------------
// bf16 MFMA GEMM, 128x64 tile, BK=64, double-buffered LDS, 2-phase prefetch.
// Global-side XOR chunk swizzle; 4 waves x acc[2][4].
// MODE 1 (qkv): bx<16  -> fused rope+QSCALE on Q  -> qkvb (bf16, std index).
//               bx==16 -> fused rope on Ksum      -> Kt[row][d].
//               bx==17 -> Vsum transpose          -> VtT[d][row].
//   All three use the R4-verified pairing: partner d^32 = acc[m][nn^2][r]
//   in the SAME thread (bit5 of column offset == bit1 of nn).
// MODE 2 (out): f32 C write.   [R6 config — best measured total 175.4]
// ---------------------------------------------------------------------------
template <int MODE>
__global__ __launch_bounds__(256) void gemm128p(const ushort* __restrict__ A,
                                                const ushort* __restrict__ Bt,
                                                void* __restrict__ Cv,
                                                ushort* __restrict__ Kt,
                                                ushort* __restrict__ VtT,
                                                int M, int N, int K) {
    __shared__ __align__(16) ushort As[2][128 * 64];
    __shared__ __align__(16) ushort Bs[2][64 * 64];

    const int tid = threadIdx.x, wave = tid >> 6, lane = tid & 63;
    const int g = lane >> 4, c = lane & 15;
    const int m0 = blockIdx.y * 128, n0 = blockIdx.x * 64;

    const int lr = tid >> 3;                 // row within 32-row slab
    const int lq = tid & 7;                  // 16B-chunk slot within row
    const int gsw = (lq ^ (lr & 7)) * 8;     // global-side XOR chunk swizzle
    const ushort* pa = A  + (size_t)(m0 + lr) * K + gsw;
    const ushort* pb = Bt + (size_t)(n0 + lr) * K + gsw;

    auto stage = [&](int buf, int k0) {
        #pragma unroll
        for (int i = 0; i < 4; ++i)
            __builtin_amdgcn_global_load_lds(
                (const __attribute__((address_space(1))) void*)(pa + (size_t)i * 32 * K + k0),
                (__attribute__((address_space(3))) void*)&As[buf][(i * 32 + wave * 8) * 64], 16, 0, 0);
        #pragma unroll
        for (int i = 0; i < 2; ++i)
            __builtin_amdgcn_global_load_lds(
                (const __attribute__((address_space(1))) void*)(pb + (size_t)i * 32 * K + k0),
                (__attribute__((address_space(3))) void*)&Bs[buf][(i * 32 + wave * 8) * 64], 16, 0, 0);
    };

    float4v acc[2][4];
    #pragma unroll
    for (int m = 0; m < 2; ++m)
        #pragma unroll
        for (int n = 0; n < 4; ++n) acc[m][n] = {0, 0, 0, 0};

    stage(0, 0);
    __syncthreads();

    const int NT = K >> 6;
    int cur = 0;
    for (int t = 0; t < NT; ++t) {
        if (t + 1 < NT) stage(cur ^ 1, (t + 1) << 6);

        #pragma unroll
        for (int kk = 0; kk < 2; ++kk) {
            const int c7 = c & 7;
            short8 af[2], bf[4];
            #pragma unroll
            for (int m = 0; m < 2; ++m)
                af[m] = *(const short8*)&As[cur][(wave * 32 + m * 16 + c) * 64 + ((kk * 4 + g) ^ c7) * 8];
            #pragma unroll
            for (int n = 0; n < 4; ++n)
                bf[n] = *(const short8*)&Bs[cur][(n * 16 + c) * 64 + ((kk * 4 + g) ^ c7) * 8];
            #pragma unroll
            for (int m = 0; m < 2; ++m)
                #pragma unroll
                for (int n = 0; n < 4; ++n)
                    acc[m][n] = __builtin_amdgcn_mfma_f32_16x16x32_bf16(af[m], bf[n], acc[m][n], 0, 0, 0);
        }
        __syncthreads();   // drains vmcnt(0): next buffer's loads landed
        cur ^= 1;
    }

    if (MODE == 1) {
        if (blockIdx.x < 16) {
            // fused rope + QSCALE on Q: qkvb[rowi][bx*64 + d], d = nn*16+c
            const float invf_e = __powf(10000.0f, -(float)c * (1.0f / 32.0f));
            const float invf_o = __powf(10000.0f, -(float)(c + 16) * (1.0f / 32.0f));
            #pragma unroll
            for (int m = 0; m < 2; ++m)
                #pragma unroll
                for (int r = 0; r < 4; ++r) {
                    const int rowi = m0 + wave * 32 + m * 16 + 4 * g + r;
                    const float nf = (float)(rowi & (N_ - 1));
                    float sn0, cs0, sn1, cs1;
                    __sincosf(nf * invf_e, &sn0, &cs0);
                    __sincosf(nf * invf_o, &sn1, &cs1);
                    #pragma unroll
                    for (int nn = 0; nn < 4; ++nn) {
                        const float v = acc[m][nn][r], p = acc[m][nn ^ 2][r];
                        const float rh = (nn < 2) ? -p : p;
                        const float sn = (nn & 1) ? sn1 : sn0;
                        const float cs = (nn & 1) ? cs1 : cs0;
                        ((ushort*)Cv)[(size_t)rowi * N + n0 + nn * 16 + c] =
                            f2bf((v * cs + rh * sn) * QSCALE);
                    }
                }
            return;
        }
        if (blockIdx.x == 16) {
            // fused rope on Ksum: Kt[rowi][d] = k*cos + rot_half(k)*sin
            const float invf_e = __powf(10000.0f, -(float)c * (1.0f / 32.0f));
            const float invf_o = __powf(10000.0f, -(float)(c + 16) * (1.0f / 32.0f));
            #pragma unroll
            for (int m = 0; m < 2; ++m)
                #pragma unroll
                for (int r = 0; r < 4; ++r) {
                    const int rowi = m0 + wave * 32 + m * 16 + 4 * g + r;
                    const float nf = (float)(rowi & (N_ - 1));
                    float sn0, cs0, sn1, cs1;
                    __sincosf(nf * invf_e, &sn0, &cs0);
                    __sincosf(nf * invf_o, &sn1, &cs1);
                    #pragma unroll
                    for (int nn = 0; nn < 4; ++nn) {
                        const float v = acc[m][nn][r], p = acc[m][nn ^ 2][r];
                        const float rh = (nn < 2) ? -p : p;
                        const float sn = (nn & 1) ? sn1 : sn0;
                        const float cs = (nn & 1) ? cs1 : cs0;
                        Kt[(size_t)rowi * 64 + nn * 16 + c] = f2bf(v * cs + rh * sn);
                    }
                }
        } else {
            // Vsum transpose: VtT[b][d][n]
            #pragma unroll
            for (int m = 0; m < 2; ++m)
                #pragma unroll
                for (int nn = 0; nn < 4; ++nn)
                    #pragma unroll
                    for (int r = 0; r < 4; ++r) {
                        const int rowi = m0 + wave * 32 + m * 16 + 4 * g + r;
                        const int n = rowi & (N_ - 1), bb = rowi >> 11;
                        VtT[((size_t)bb * 64 + nn * 16 + c) * N_ + n] = f2bf(acc[m][nn][r]);
                    }
        }
        return;
    }

    #pragma unroll
    for (int m = 0; m < 2; ++m)
        #pragma unroll
        for (int n = 0; n < 4; ++n)
            #pragma unroll
            for (int r = 0; r < 4; ++r) {
                int rowi = m0 + wave * 32 + m * 16 + 4 * g + r;
                int coli = n0 + n * 16 + c;
                ((float*)Cv)[(size_t)rowi * N + coli] = acc[m][n][r];
            }
}

// ---------------------------------------------------------------------------
// Flash attention v17: SINGLE-PASS (no K-split, no combine kernel).
// 512 threads / 8 waves, each wave owns 32 Q-rows (attn16's shape, measured
// equivalent to attn14). One block per (b,h,qt) iterates ALL 2048 j's
// (NT=32), so ll is the complete softmax denominator and the epilogue
// writes the final normalized bf16 output directly to ao.
// Deletes: combine kernel + launch gap, oP1 partial (8.4MB w + 16.8MB r),
// lP traffic. Grid 256 = 1 block/CU; 2 waves/SIMD (occupancy-insensitivity
// established in R8/R9).
// ---------------------------------------------------------------------------
__global__ __launch_bounds__(512) void attn17(
        const ushort* __restrict__ qkvb, const ushort* __restrict__ Kt,
        const ushort* __restrict__ VtT, ushort* __restrict__ ao) {
    const int qt = blockIdx.x & 7;
    const int h  = (blockIdx.x >> 3) & 15;
    const int b  = blockIdx.x >> 7;
    const int tid = threadIdx.x, wave = tid >> 6, lane = tid & 63;
    const int g = lane >> 4, c = lane & 15;

    __shared__ __align__(16) ushort Ksh[64 * 64];   // [j-local][d], XOR-swizzled
    __shared__ __align__(16) ushort Vsh[64 * 64];   // [d][j-local], XOR-swizzled

    const int i0 = qt * 256 + wave * 32;

    short8 qf[2][2];
    #pragma unroll
    for (int a = 0; a < 2; ++a) {
        const int row = i0 + a * 16 + c;
        const ushort* qrow = qkvb + (size_t)(b * N_ + row) * QKV_N + h * 64;
        qf[a][0] = *(const short8*)(qrow + 8 * g);
        qf[a][1] = *(const short8*)(qrow + 32 + 8 * g);
    }

    float4v o[2][4];
    #pragma unroll
    for (int a = 0; a < 2; ++a)
        #pragma unroll
        for (int f = 0; f < 4; ++f) o[a][f] = {0, 0, 0, 0};
    float ll[2] = {0.f, 0.f};

    const ushort* Kb = Kt  + (size_t)b * N_ * 64;
    const ushort* Vb = VtT + (size_t)b * 64 * N_;
    const int lr8 = lane >> 3, lq8 = lane & 7;
    const int wpos = (lq8 ^ lr8) * 8;
    const int NT = N_ / 64;

    // each wave stages 8 rows of K ([j][d]) and 8 rows of V ([d][j])
    short8 kr0 = *(const short8*)(Kb + (size_t)(wave * 8 + lr8) * 64 + lq8 * 8);
    short8 vr0 = *(const short8*)(Vb + (size_t)(wave * 8 + lr8) * N_ + lq8 * 8);

    for (int t = 0; t < NT; ++t) {
        __syncthreads();
        *(short8*)&Ksh[(wave * 8 + lr8) * 64 + wpos] = kr0;
        *(short8*)&Vsh[(wave * 8 + lr8) * 64 + wpos] = vr0;
        __syncthreads();
        if (t + 1 < NT) {
            const int jn = (t + 1) * 64;
            kr0 = *(const short8*)(Kb + (size_t)(jn + wave * 8 + lr8) * 64 + lq8 * 8);
            vr0 = *(const short8*)(Vb + (size_t)(wave * 8 + lr8) * N_ + jn + lq8 * 8);
        }

        #pragma unroll
        for (int jt4 = 0; jt4 < 4; ++jt4) {
            const int R = jt4 * 16 + c;
            short8 kf0 = *(const short8*)&Ksh[R * 64 + ((g ^ (c & 7)) * 8)];
            short8 kf1 = *(const short8*)&Ksh[R * 64 + (((g ^ 4) ^ (c & 7)) * 8)];
            short4v vf[4];
            #pragma unroll
            for (int f = 0; f < 4; ++f)
                vf[f] = *(const short4v*)&Vsh[(16 * f + c) * 64 +
                          (((jt4 * 2 + (g >> 1)) ^ (c & 7)) * 8) + (g & 1) * 4];

            #pragma unroll
            for (int a = 0; a < 2; ++a) {
                float4v st = {0, 0, 0, 0};
                st = __builtin_amdgcn_mfma_f32_16x16x32_bf16(kf0, qf[a][0], st, 0, 0, 0);
                st = __builtin_amdgcn_mfma_f32_16x16x32_bf16(kf1, qf[a][1], st, 0, 0, 0);
                float p0 = fexp2(st[0]), p1 = fexp2(st[1]);
                float p2 = fexp2(st[2]), p3 = fexp2(st[3]);
                ll[a] += (p0 + p1) + (p2 + p3);
                union { unsigned u[2]; short4v v; } pk;
                pk.u[0] = pack_bf16(p0, p1);
                pk.u[1] = pack_bf16(p2, p3);
                #pragma unroll
                for (int f = 0; f < 4; ++f)
                    o[a][f] = MFMA16K16(vf[f], pk.v, o[a][f]);
            }
        }
    }

    #pragma unroll
    for (int a = 0; a < 2; ++a) {
        float lt = ll[a];
        lt += __shfl_xor(lt, 16, 64);
        lt += __shfl_xor(lt, 32, 64);
        const float inv = 1.0f / lt;
        const int row = i0 + a * 16 + c;
        #pragma unroll
        for (int f = 0; f < 4; ++f) {
            ushort4 w;
            w.x = f2bf(o[a][f][0] * inv); w.y = f2bf(o[a][f][1] * inv);
            w.z = f2bf(o[a][f][2] * inv); w.w = f2bf(o[a][f][3] * inv);
            *(ushort4*)(ao + (size_t)(b * N_ + row) * 1024 + h * 64 + 16 * f + 4 * g) = w;
        }
    }
}

// ---------------------------------------------------------------------------
extern "C" void kernel_launch(void* const* d_in, const int* in_sizes, int n_in,
                              void* d_out, int out_size, void* d_ws, size_t ws_size,
                              hipStream_t stream) {
    const float* x     = (const float*)d_in[0];
    const float* w_q   = (const float*)d_in[1];
    const float* w_kv  = (const float*)d_in[2];
    const float* w_out = (const float*)d_in[3];
    float* out = (float*)d_out;

    const int M = B_ * N_;                               // 4096
    ushort* xb    = (ushort*)d_ws;                       // 4096*1024  (-> ao)
    ushort* wqkvT = xb    + (size_t)M * C_;              // 1152*1024
    ushort* woutT = wqkvT + (size_t)QKV_N * C_;          // 1024*1024
    ushort* qkvb  = woutT + (size_t)C_ * C_;             // 4096*1152
    ushort* Kt    = qkvb  + (size_t)M * QKV_N;           // 2*2048*64
    ushort* VtT   = Kt    + (size_t)B_ * N_ * D_;        // 2*64*2048
    ushort* ao    = xb;   // xb dead after qkv GEMM; attn writes final here

    prep<<<4624, 256, 0, stream>>>(x, w_q, w_kv, w_out, xb, wqkvT, woutT);
    gemm128p<1><<<dim3(QKV_N / 64, M / 128), 256, 0, stream>>>(xb, wqkvT, qkvb, Kt, VtT, M, QKV_N, C_);
    attn17<<<B_ * H_ * (N_ / 256), 512, 0, stream>>>(qkvb, Kt, VtT, ao);
    gemm128p<2><<<dim3(C_ / 64, M / 128), 256, 0, stream>>>(ao, woutT, out, nullptr, nullptr, M, C_, C_);
}

// Round 11
// 169.883 us; speedup vs baseline: 1.0581x; 1.0122x over previous
//
#include <hip/hip_runtime.h>
#include <hip/hip_bf16.h>
#include <math.h>

#define B_ 2
#define N_ 2048
#define C_ 1024
#define H_ 16
#define G_ 4
#define D_ 64
#define QKV_N 1152   // 1024 q + 64 ksum + 64 vsum

#define QSCALE 0.18033688011112042f   // 0.125 * log2(e)

using short8  = __attribute__((ext_vector_type(8))) short;
using short4v = __attribute__((ext_vector_type(4))) short;
using float4v = __attribute__((ext_vector_type(4))) float;

#if __has_builtin(__builtin_amdgcn_mfma_f32_16x16x16_bf16)
#define MFMA16K16(A, B, C) __builtin_amdgcn_mfma_f32_16x16x16_bf16(A, B, C, 0, 0, 0)
#else
#define MFMA16K16(A, B, C) __builtin_amdgcn_mfma_f32_16x16x16bf16_1k(A, B, C, 0, 0, 0)
#endif

__device__ __forceinline__ ushort f2bf(float f) {
    union { float f; unsigned u; } v; v.f = f;
    unsigned r = (v.u + 0x7FFF + ((v.u >> 16) & 1)) >> 16;  // RNE
    return (ushort)r;
}
__device__ __forceinline__ float bf2f(ushort u) {
    union { unsigned u; float f; } t; t.u = ((unsigned)u) << 16; return t.f;
}
__device__ __forceinline__ unsigned pack_bf16(float a, float b) {
#if __has_builtin(__builtin_amdgcn_cvt_pk_bf16_f32)
    auto t = __builtin_amdgcn_cvt_pk_bf16_f32(a, b);
    unsigned r; __builtin_memcpy(&r, &t, 4); return r;
#else
    return (unsigned)f2bf(a) | ((unsigned)f2bf(b) << 16);
#endif
}
__device__ __forceinline__ float fexp2(float x) {
#if __has_builtin(__builtin_amdgcn_exp2f)
    return __builtin_amdgcn_exp2f(x);
#else
    return exp2f(x);
#endif
}

// ---------------------------------------------------------------------------
// Fused prep (one launch):
//   blocks [0,4096)     : x fp32 -> bf16
//   [4096,4352)         : w_q^T   -> wqkvT rows 0..1023
//   [4352,4608)         : w_out^T -> woutT
//   [4608,4624)         : kv weight g-sum + transpose -> wqkvT rows 1024..1151
// ---------------------------------------------------------------------------
__device__ void tconv_body(const float* __restrict__ src, ushort* __restrict__ dst,
                           int K, int N, int bx, int by, float (*T)[65]) {
    const int n0 = bx * 64, k0 = by * 64;
    const int tid = threadIdx.x;
    #pragma unroll
    for (int s = 0; s < 16; ++s) {
        int idx = tid + s * 256; int r = idx >> 6, cc = idx & 63;
        T[r][cc] = src[(size_t)(k0 + r) * N + n0 + cc];
    }
    __syncthreads();
    #pragma unroll
    for (int s = 0; s < 16; ++s) {
        int idx = tid + s * 256; int r = idx >> 6, cc = idx & 63;
        dst[(size_t)(n0 + r) * K + k0 + cc] = f2bf(T[cc][r]);
    }
}

__global__ void prep(const float* __restrict__ x, const float* __restrict__ w_q,
                     const float* __restrict__ w_kv, const float* __restrict__ w_out,
                     ushort* __restrict__ xb, ushort* __restrict__ wqkvT,
                     ushort* __restrict__ woutT) {
    __shared__ float T[64][65];
    const int blk = blockIdx.x, tid = threadIdx.x;
    if (blk < 4096) {
        int i = blk * 1024 + tid * 4;
        float4 v = *(const float4*)(x + i);
        ushort4 o;
        o.x = f2bf(v.x); o.y = f2bf(v.y); o.z = f2bf(v.z); o.w = f2bf(v.w);
        *(ushort4*)(xb + i) = o;
    } else if (blk < 4352) {
        int idx = blk - 4096;
        tconv_body(w_q, wqkvT, C_, C_, idx & 15, idx >> 4, T);
    } else if (blk < 4608) {
        int idx = blk - 4352;
        tconv_body(w_out, woutT, C_, C_, idx & 15, idx >> 4, T);
    } else {
        // kv g-sum + transpose: wqkvT[1024+d][k] = sum_g w_kv[k][g*64+d],
        //                       wqkvT[1088+d][k] = sum_g w_kv[k][256+g*64+d]
        const int k0 = (blk - 4608) * 64;
        #pragma unroll
        for (int it = 0; it < 4; ++it) {
            int p = tid + it * 256;              // 1024 (kk, d-quad) pairs
            int kk = p >> 4, d4 = (p & 15) * 4;
            float ks[4] = {0, 0, 0, 0}, vs[4] = {0, 0, 0, 0};
            #pragma unroll
            for (int g = 0; g < G_; ++g) {
                float4 a = *(const float4*)(w_kv + (size_t)(k0 + kk) * 512 + g * 64 + d4);
                float4 b = *(const float4*)(w_kv + (size_t)(k0 + kk) * 512 + 256 + g * 64 + d4);
                ks[0] += a.x; ks[1] += a.y; ks[2] += a.z; ks[3] += a.w;
                vs[0] += b.x; vs[1] += b.y; vs[2] += b.z; vs[3] += b.w;
            }
            #pragma unroll
            for (int e = 0; e < 4; ++e) {
                wqkvT[(size_t)(1024 + d4 + e) * C_ + k0 + kk] = f2bf(ks[e]);
                wqkvT[(size_t)(1088 + d4 + e) * C_ + k0 + kk] = f2bf(vs[e]);
            }
        }
    }
}

// ---------------------------------------------------------------------------
// bf16 MFMA GEMM, 128x64 tile, BK=64, double-buffered LDS, 2-phase prefetch.
// Global-side XOR chunk swizzle; 4 waves x acc[2][4].
// NEW (R11): 1-D launch + XCD-locality tile remap (T1). Under round-robin
// workgroup->XCD dispatch, xcd = L&7; we give each XCD a contiguous 4-panel
// by-chunk so the A-panels it re-reads stay in its private L2:
//   by = (L&7)*4 + (L>>3)%4,  bx = (L>>3)/4      (bijective: 8*4*BXN = grid)
// A-panel footprint per XCD = 4*256KB = 1MB (fits 4MB L2). A HBM traffic
// drops from ~BXN x 8MB to ~8MB. Mechanism matches the R8 observation that
// GEMM compute-structure variants were all neutral (panel-refetch-bound).
// MODE 1 (qkv): bx<16  -> fused rope+QSCALE on Q  -> qkvb.
//               bx==16 -> fused rope on Ksum      -> Kt[row][d].
//               bx==17 -> Vsum transpose          -> VtT[d][row].
// MODE 2 (out): f32 C write.
// ---------------------------------------------------------------------------
template <int MODE>
__global__ __launch_bounds__(256) void gemm128p(const ushort* __restrict__ A,
                                                const ushort* __restrict__ Bt,
                                                void* __restrict__ Cv,
                                                ushort* __restrict__ Kt,
                                                ushort* __restrict__ VtT,
                                                int M, int N, int K) {
    __shared__ __align__(16) ushort As[2][128 * 64];
    __shared__ __align__(16) ushort Bs[2][64 * 64];

    const int tid = threadIdx.x, wave = tid >> 6, lane = tid & 63;
    const int g = lane >> 4, c = lane & 15;

    // XCD-locality remap (NBY = M/128 is 32 for both GEMMs; 32/8 = 4)
    const int L = blockIdx.x;
    const int xcd = L & 7, local = L >> 3;
    const int by = xcd * 4 + (local & 3);
    const int bx = local >> 2;
    const int m0 = by * 128, n0 = bx * 64;

    const int lr = tid >> 3;                 // row within 32-row slab
    const int lq = tid & 7;                  // 16B-chunk slot within row
    const int gsw = (lq ^ (lr & 7)) * 8;     // global-side XOR chunk swizzle
    const ushort* pa = A  + (size_t)(m0 + lr) * K + gsw;
    const ushort* pb = Bt + (size_t)(n0 + lr) * K + gsw;

    auto stage = [&](int buf, int k0) {
        #pragma unroll
        for (int i = 0; i < 4; ++i)
            __builtin_amdgcn_global_load_lds(
                (const __attribute__((address_space(1))) void*)(pa + (size_t)i * 32 * K + k0),
                (__attribute__((address_space(3))) void*)&As[buf][(i * 32 + wave * 8) * 64], 16, 0, 0);
        #pragma unroll
        for (int i = 0; i < 2; ++i)
            __builtin_amdgcn_global_load_lds(
                (const __attribute__((address_space(1))) void*)(pb + (size_t)i * 32 * K + k0),
                (__attribute__((address_space(3))) void*)&Bs[buf][(i * 32 + wave * 8) * 64], 16, 0, 0);
    };

    float4v acc[2][4];
    #pragma unroll
    for (int m = 0; m < 2; ++m)
        #pragma unroll
        for (int n = 0; n < 4; ++n) acc[m][n] = {0, 0, 0, 0};

    stage(0, 0);
    __syncthreads();

    const int NT = K >> 6;
    int cur = 0;
    for (int t = 0; t < NT; ++t) {
        if (t + 1 < NT) stage(cur ^ 1, (t + 1) << 6);

        #pragma unroll
        for (int kk = 0; kk < 2; ++kk) {
            const int c7 = c & 7;
            short8 af[2], bf[4];
            #pragma unroll
            for (int m = 0; m < 2; ++m)
                af[m] = *(const short8*)&As[cur][(wave * 32 + m * 16 + c) * 64 + ((kk * 4 + g) ^ c7) * 8];
            #pragma unroll
            for (int n = 0; n < 4; ++n)
                bf[n] = *(const short8*)&Bs[cur][(n * 16 + c) * 64 + ((kk * 4 + g) ^ c7) * 8];
            #pragma unroll
            for (int m = 0; m < 2; ++m)
                #pragma unroll
                for (int n = 0; n < 4; ++n)
                    acc[m][n] = __builtin_amdgcn_mfma_f32_16x16x32_bf16(af[m], bf[n], acc[m][n], 0, 0, 0);
        }
        __syncthreads();   // drains vmcnt(0): next buffer's loads landed
        cur ^= 1;
    }

    if (MODE == 1) {
        if (bx < 16) {
            // fused rope + QSCALE on Q: qkvb[rowi][bx*64 + d], d = nn*16+c
            const float invf_e = __powf(10000.0f, -(float)c * (1.0f / 32.0f));
            const float invf_o = __powf(10000.0f, -(float)(c + 16) * (1.0f / 32.0f));
            #pragma unroll
            for (int m = 0; m < 2; ++m)
                #pragma unroll
                for (int r = 0; r < 4; ++r) {
                    const int rowi = m0 + wave * 32 + m * 16 + 4 * g + r;
                    const float nf = (float)(rowi & (N_ - 1));
                    float sn0, cs0, sn1, cs1;
                    __sincosf(nf * invf_e, &sn0, &cs0);
                    __sincosf(nf * invf_o, &sn1, &cs1);
                    #pragma unroll
                    for (int nn = 0; nn < 4; ++nn) {
                        const float v = acc[m][nn][r], p = acc[m][nn ^ 2][r];
                        const float rh = (nn < 2) ? -p : p;
                        const float sn = (nn & 1) ? sn1 : sn0;
                        const float cs = (nn & 1) ? cs1 : cs0;
                        ((ushort*)Cv)[(size_t)rowi * N + n0 + nn * 16 + c] =
                            f2bf((v * cs + rh * sn) * QSCALE);
                    }
                }
            return;
        }
        if (bx == 16) {
            // fused rope on Ksum: Kt[rowi][d] = k*cos + rot_half(k)*sin
            const float invf_e = __powf(10000.0f, -(float)c * (1.0f / 32.0f));
            const float invf_o = __powf(10000.0f, -(float)(c + 16) * (1.0f / 32.0f));
            #pragma unroll
            for (int m = 0; m < 2; ++m)
                #pragma unroll
                for (int r = 0; r < 4; ++r) {
                    const int rowi = m0 + wave * 32 + m * 16 + 4 * g + r;
                    const float nf = (float)(rowi & (N_ - 1));
                    float sn0, cs0, sn1, cs1;
                    __sincosf(nf * invf_e, &sn0, &cs0);
                    __sincosf(nf * invf_o, &sn1, &cs1);
                    #pragma unroll
                    for (int nn = 0; nn < 4; ++nn) {
                        const float v = acc[m][nn][r], p = acc[m][nn ^ 2][r];
                        const float rh = (nn < 2) ? -p : p;
                        const float sn = (nn & 1) ? sn1 : sn0;
                        const float cs = (nn & 1) ? cs1 : cs0;
                        Kt[(size_t)rowi * 64 + nn * 16 + c] = f2bf(v * cs + rh * sn);
                    }
                }
        } else {
            // Vsum transpose: VtT[b][d][n]
            #pragma unroll
            for (int m = 0; m < 2; ++m)
                #pragma unroll
                for (int nn = 0; nn < 4; ++nn)
                    #pragma unroll
                    for (int r = 0; r < 4; ++r) {
                        const int rowi = m0 + wave * 32 + m * 16 + 4 * g + r;
                        const int n = rowi & (N_ - 1), bb = rowi >> 11;
                        VtT[((size_t)bb * 64 + nn * 16 + c) * N_ + n] = f2bf(acc[m][nn][r]);
                    }
        }
        return;
    }

    #pragma unroll
    for (int m = 0; m < 2; ++m)
        #pragma unroll
        for (int n = 0; n < 4; ++n)
            #pragma unroll
            for (int r = 0; r < 4; ++r) {
                int rowi = m0 + wave * 32 + m * 16 + 4 * g + r;
                int coli = n0 + n * 16 + c;
                ((float*)Cv)[(size_t)rowi * N + coli] = acc[m][n][r];
            }
}

// ---------------------------------------------------------------------------
// Flash attention v17: SINGLE-PASS (no K-split, no combine kernel).
// [R10-proven: 60.3 us, best attn; unchanged this round]
// ---------------------------------------------------------------------------
__global__ __launch_bounds__(512) void attn17(
        const ushort* __restrict__ qkvb, const ushort* __restrict__ Kt,
        const ushort* __restrict__ VtT, ushort* __restrict__ ao) {
    const int qt = blockIdx.x & 7;
    const int h  = (blockIdx.x >> 3) & 15;
    const int b  = blockIdx.x >> 7;
    const int tid = threadIdx.x, wave = tid >> 6, lane = tid & 63;
    const int g = lane >> 4, c = lane & 15;

    __shared__ __align__(16) ushort Ksh[64 * 64];   // [j-local][d], XOR-swizzled
    __shared__ __align__(16) ushort Vsh[64 * 64];   // [d][j-local], XOR-swizzled

    const int i0 = qt * 256 + wave * 32;

    short8 qf[2][2];
    #pragma unroll
    for (int a = 0; a < 2; ++a) {
        const int row = i0 + a * 16 + c;
        const ushort* qrow = qkvb + (size_t)(b * N_ + row) * QKV_N + h * 64;
        qf[a][0] = *(const short8*)(qrow + 8 * g);
        qf[a][1] = *(const short8*)(qrow + 32 + 8 * g);
    }

    float4v o[2][4];
    #pragma unroll
    for (int a = 0; a < 2; ++a)
        #pragma unroll
        for (int f = 0; f < 4; ++f) o[a][f] = {0, 0, 0, 0};
    float ll[2] = {0.f, 0.f};

    const ushort* Kb = Kt  + (size_t)b * N_ * 64;
    const ushort* Vb = VtT + (size_t)b * 64 * N_;
    const int lr8 = lane >> 3, lq8 = lane & 7;
    const int wpos = (lq8 ^ lr8) * 8;
    const int NT = N_ / 64;

    // each wave stages 8 rows of K ([j][d]) and 8 rows of V ([d][j])
    short8 kr0 = *(const short8*)(Kb + (size_t)(wave * 8 + lr8) * 64 + lq8 * 8);
    short8 vr0 = *(const short8*)(Vb + (size_t)(wave * 8 + lr8) * N_ + lq8 * 8);

    for (int t = 0; t < NT; ++t) {
        __syncthreads();
        *(short8*)&Ksh[(wave * 8 + lr8) * 64 + wpos] = kr0;
        *(short8*)&Vsh[(wave * 8 + lr8) * 64 + wpos] = vr0;
        __syncthreads();
        if (t + 1 < NT) {
            const int jn = (t + 1) * 64;
            kr0 = *(const short8*)(Kb + (size_t)(jn + wave * 8 + lr8) * 64 + lq8 * 8);
            vr0 = *(const short8*)(Vb + (size_t)(wave * 8 + lr8) * N_ + jn + lq8 * 8);
        }

        #pragma unroll
        for (int jt4 = 0; jt4 < 4; ++jt4) {
            const int R = jt4 * 16 + c;
            short8 kf0 = *(const short8*)&Ksh[R * 64 + ((g ^ (c & 7)) * 8)];
            short8 kf1 = *(const short8*)&Ksh[R * 64 + (((g ^ 4) ^ (c & 7)) * 8)];
            short4v vf[4];
            #pragma unroll
            for (int f = 0; f < 4; ++f)
                vf[f] = *(const short4v*)&Vsh[(16 * f + c) * 64 +
                          (((jt4 * 2 + (g >> 1)) ^ (c & 7)) * 8) + (g & 1) * 4];

            #pragma unroll
            for (int a = 0; a < 2; ++a) {
                float4v st = {0, 0, 0, 0};
                st = __builtin_amdgcn_mfma_f32_16x16x32_bf16(kf0, qf[a][0], st, 0, 0, 0);
                st = __builtin_amdgcn_mfma_f32_16x16x32_bf16(kf1, qf[a][1], st, 0, 0, 0);
                float p0 = fexp2(st[0]), p1 = fexp2(st[1]);
                float p2 = fexp2(st[2]), p3 = fexp2(st[3]);
                ll[a] += (p0 + p1) + (p2 + p3);
                union { unsigned u[2]; short4v v; } pk;
                pk.u[0] = pack_bf16(p0, p1);
                pk.u[1] = pack_bf16(p2, p3);
                #pragma unroll
                for (int f = 0; f < 4; ++f)
                    o[a][f] = MFMA16K16(vf[f], pk.v, o[a][f]);
            }
        }
    }

    #pragma unroll
    for (int a = 0; a < 2; ++a) {
        float lt = ll[a];
        lt += __shfl_xor(lt, 16, 64);
        lt += __shfl_xor(lt, 32, 64);
        const float inv = 1.0f / lt;
        const int row = i0 + a * 16 + c;
        #pragma unroll
        for (int f = 0; f < 4; ++f) {
            ushort4 w;
            w.x = f2bf(o[a][f][0] * inv); w.y = f2bf(o[a][f][1] * inv);
            w.z = f2bf(o[a][f][2] * inv); w.w = f2bf(o[a][f][3] * inv);
            *(ushort4*)(ao + (size_t)(b * N_ + row) * 1024 + h * 64 + 16 * f + 4 * g) = w;
        }
    }
}

// ---------------------------------------------------------------------------
extern "C" void kernel_launch(void* const* d_in, const int* in_sizes, int n_in,
                              void* d_out, int out_size, void* d_ws, size_t ws_size,
                              hipStream_t stream) {
    const float* x     = (const float*)d_in[0];
    const float* w_q   = (const float*)d_in[1];
    const float* w_kv  = (const float*)d_in[2];
    const float* w_out = (const float*)d_in[3];
    float* out = (float*)d_out;

    const int M = B_ * N_;                               // 4096
    ushort* xb    = (ushort*)d_ws;                       // 4096*1024  (-> ao)
    ushort* wqkvT = xb    + (size_t)M * C_;              // 1152*1024
    ushort* woutT = wqkvT + (size_t)QKV_N * C_;          // 1024*1024
    ushort* qkvb  = woutT + (size_t)C_ * C_;             // 4096*1152
    ushort* Kt    = qkvb  + (size_t)M * QKV_N;           // 2*2048*64
    ushort* VtT   = Kt    + (size_t)B_ * N_ * D_;        // 2*64*2048
    ushort* ao    = xb;   // xb dead after qkv GEMM; attn writes final here

    prep<<<4624, 256, 0, stream>>>(x, w_q, w_kv, w_out, xb, wqkvT, woutT);
    gemm128p<1><<<(QKV_N / 64) * (M / 128), 256, 0, stream>>>(xb, wqkvT, qkvb, Kt, VtT, M, QKV_N, C_);
    attn17<<<B_ * H_ * (N_ / 256), 512, 0, stream>>>(qkvb, Kt, VtT, ao);
    gemm128p<2><<<(C_ / 64) * (M / 128), 256, 0, stream>>>(ao, woutT, out, nullptr, nullptr, M, C_, C_);
}

// Round 12
// 168.839 us; speedup vs baseline: 1.0647x; 1.0062x over previous
//
#include <hip/hip_runtime.h>
#include <hip/hip_bf16.h>
#include <math.h>

#define B_ 2
#define N_ 2048
#define C_ 1024
#define H_ 16
#define G_ 4
#define D_ 64
#define QKV_N 1152   // 1024 q + 64 ksum + 64 vsum

#define QSCALE 0.18033688011112042f   // 0.125 * log2(e)

using short8  = __attribute__((ext_vector_type(8))) short;
using short4v = __attribute__((ext_vector_type(4))) short;
using float4v = __attribute__((ext_vector_type(4))) float;

#if __has_builtin(__builtin_amdgcn_mfma_f32_16x16x16_bf16)
#define MFMA16K16(A, B, C) __builtin_amdgcn_mfma_f32_16x16x16_bf16(A, B, C, 0, 0, 0)
#else
#define MFMA16K16(A, B, C) __builtin_amdgcn_mfma_f32_16x16x16bf16_1k(A, B, C, 0, 0, 0)
#endif

__device__ __forceinline__ ushort f2bf(float f) {
    union { float f; unsigned u; } v; v.f = f;
    unsigned r = (v.u + 0x7FFF + ((v.u >> 16) & 1)) >> 16;  // RNE
    return (ushort)r;
}
__device__ __forceinline__ float bf2f(ushort u) {
    union { unsigned u; float f; } t; t.u = ((unsigned)u) << 16; return t.f;
}
__device__ __forceinline__ unsigned pack_bf16(float a, float b) {
#if __has_builtin(__builtin_amdgcn_cvt_pk_bf16_f32)
    auto t = __builtin_amdgcn_cvt_pk_bf16_f32(a, b);
    unsigned r; __builtin_memcpy(&r, &t, 4); return r;
#else
    return (unsigned)f2bf(a) | ((unsigned)f2bf(b) << 16);
#endif
}
__device__ __forceinline__ float fexp2(float x) {
#if __has_builtin(__builtin_amdgcn_exp2f)
    return __builtin_amdgcn_exp2f(x);
#else
    return exp2f(x);
#endif
}

// ---------------------------------------------------------------------------
// Fused prep (one launch):
//   blocks [0,4096)     : x fp32 -> bf16
//   [4096,4352)         : w_q^T   -> wqkvT rows 0..1023
//   [4352,4608)         : w_out^T -> woutT
//   [4608,4624)         : kv weight g-sum + transpose -> wqkvT rows 1024..1151
// ---------------------------------------------------------------------------
__device__ void tconv_body(const float* __restrict__ src, ushort* __restrict__ dst,
                           int K, int N, int bx, int by, float (*T)[65]) {
    const int n0 = bx * 64, k0 = by * 64;
    const int tid = threadIdx.x;
    #pragma unroll
    for (int s = 0; s < 16; ++s) {
        int idx = tid + s * 256; int r = idx >> 6, cc = idx & 63;
        T[r][cc] = src[(size_t)(k0 + r) * N + n0 + cc];
    }
    __syncthreads();
    #pragma unroll
    for (int s = 0; s < 16; ++s) {
        int idx = tid + s * 256; int r = idx >> 6, cc = idx & 63;
        dst[(size_t)(n0 + r) * K + k0 + cc] = f2bf(T[cc][r]);
    }
}

__global__ void prep(const float* __restrict__ x, const float* __restrict__ w_q,
                     const float* __restrict__ w_kv, const float* __restrict__ w_out,
                     ushort* __restrict__ xb, ushort* __restrict__ wqkvT,
                     ushort* __restrict__ woutT) {
    __shared__ float T[64][65];
    const int blk = blockIdx.x, tid = threadIdx.x;
    if (blk < 4096) {
        int i = blk * 1024 + tid * 4;
        float4 v = *(const float4*)(x + i);
        ushort4 o;
        o.x = f2bf(v.x); o.y = f2bf(v.y); o.z = f2bf(v.z); o.w = f2bf(v.w);
        *(ushort4*)(xb + i) = o;
    } else if (blk < 4352) {
        int idx = blk - 4096;
        tconv_body(w_q, wqkvT, C_, C_, idx & 15, idx >> 4, T);
    } else if (blk < 4608) {
        int idx = blk - 4352;
        tconv_body(w_out, woutT, C_, C_, idx & 15, idx >> 4, T);
    } else {
        // kv g-sum + transpose: wqkvT[1024+d][k] = sum_g w_kv[k][g*64+d],
        //                       wqkvT[1088+d][k] = sum_g w_kv[k][256+g*64+d]
        const int k0 = (blk - 4608) * 64;
        #pragma unroll
        for (int it = 0; it < 4; ++it) {
            int p = tid + it * 256;              // 1024 (kk, d-quad) pairs
            int kk = p >> 4, d4 = (p & 15) * 4;
            float ks[4] = {0, 0, 0, 0}, vs[4] = {0, 0, 0, 0};
            #pragma unroll
            for (int g = 0; g < G_; ++g) {
                float4 a = *(const float4*)(w_kv + (size_t)(k0 + kk) * 512 + g * 64 + d4);
                float4 b = *(const float4*)(w_kv + (size_t)(k0 + kk) * 512 + 256 + g * 64 + d4);
                ks[0] += a.x; ks[1] += a.y; ks[2] += a.z; ks[3] += a.w;
                vs[0] += b.x; vs[1] += b.y; vs[2] += b.z; vs[3] += b.w;
            }
            #pragma unroll
            for (int e = 0; e < 4; ++e) {
                wqkvT[(size_t)(1024 + d4 + e) * C_ + k0 + kk] = f2bf(ks[e]);
                wqkvT[(size_t)(1088 + d4 + e) * C_ + k0 + kk] = f2bf(vs[e]);
            }
        }
    }
}

// ---------------------------------------------------------------------------
// bf16 MFMA GEMM, 128x64 tile, BK=64, double-buffered LDS.
// NEW (R12): counted-vmcnt pipeline (T4) replaces the syncthreads full drain.
// 2 tiles (12 global_load_lds) stay in flight; each wave waits vmcnt(6) =
// its own oldest 6 (= current tile), then raw s_barrier makes tile t's LDS
// data globally staged (every wave retired its own portion). After compute,
// a second raw s_barrier protects the buffer before restaging; its loads
// land into a buffer nobody reads until the next counted wait. vmcnt never
// drains to 0 in the main loop (AITER pattern, plain HIP).
// Keeps: global-side XOR chunk swizzle, T1 XCD remap, 4 waves x acc[2][4].
// MODE 1 (qkv): bx<16  -> fused rope+QSCALE on Q  -> qkvb.
//               bx==16 -> fused rope on Ksum      -> Kt[row][d].
//               bx==17 -> Vsum transpose          -> VtT[d][row].
// MODE 2 (out): f32 C write.
// ---------------------------------------------------------------------------
template <int MODE>
__global__ __launch_bounds__(256) void gemm128p(const ushort* __restrict__ A,
                                                const ushort* __restrict__ Bt,
                                                void* __restrict__ Cv,
                                                ushort* __restrict__ Kt,
                                                ushort* __restrict__ VtT,
                                                int M, int N, int K) {
    __shared__ __align__(16) ushort As[2][128 * 64];
    __shared__ __align__(16) ushort Bs[2][64 * 64];

    const int tid = threadIdx.x, wave = tid >> 6, lane = tid & 63;
    const int g = lane >> 4, c = lane & 15;

    // XCD-locality remap (T1, R11: +2us): by-chunks of 4 per XCD
    const int L = blockIdx.x;
    const int xcd = L & 7, local = L >> 3;
    const int by = xcd * 4 + (local & 3);
    const int bx = local >> 2;
    const int m0 = by * 128, n0 = bx * 64;

    const int lr = tid >> 3;                 // row within 32-row slab
    const int lq = tid & 7;                  // 16B-chunk slot within row
    const int gsw = (lq ^ (lr & 7)) * 8;     // global-side XOR chunk swizzle
    const ushort* pa = A  + (size_t)(m0 + lr) * K + gsw;
    const ushort* pb = Bt + (size_t)(n0 + lr) * K + gsw;

    auto stage = [&](int buf, int k0) {
        #pragma unroll
        for (int i = 0; i < 4; ++i)
            __builtin_amdgcn_global_load_lds(
                (const __attribute__((address_space(1))) void*)(pa + (size_t)i * 32 * K + k0),
                (__attribute__((address_space(3))) void*)&As[buf][(i * 32 + wave * 8) * 64], 16, 0, 0);
        #pragma unroll
        for (int i = 0; i < 2; ++i)
            __builtin_amdgcn_global_load_lds(
                (const __attribute__((address_space(1))) void*)(pb + (size_t)i * 32 * K + k0),
                (__attribute__((address_space(3))) void*)&Bs[buf][(i * 32 + wave * 8) * 64], 16, 0, 0);
    };

    float4v acc[2][4];
    #pragma unroll
    for (int m = 0; m < 2; ++m)
        #pragma unroll
        for (int n = 0; n < 4; ++n) acc[m][n] = {0, 0, 0, 0};

    const int NT = K >> 6;                   // 16 for K=1024
    stage(0, 0);
    stage(1, 64);                            // 12 loads in flight

    for (int t = 0; t < NT; ++t) {
        if (t + 1 < NT) {
            asm volatile("s_waitcnt vmcnt(6)" ::: "memory");   // own tile-t loads done
        } else {
            asm volatile("s_waitcnt vmcnt(0)" ::: "memory");   // final tile: drain
        }
        __builtin_amdgcn_s_barrier();        // all waves staged tile t

        const int cur = t & 1;
        #pragma unroll
        for (int kk = 0; kk < 2; ++kk) {
            const int c7 = c & 7;
            short8 af[2], bf[4];
            #pragma unroll
            for (int m = 0; m < 2; ++m)
                af[m] = *(const short8*)&As[cur][(wave * 32 + m * 16 + c) * 64 + ((kk * 4 + g) ^ c7) * 8];
            #pragma unroll
            for (int n = 0; n < 4; ++n)
                bf[n] = *(const short8*)&Bs[cur][(n * 16 + c) * 64 + ((kk * 4 + g) ^ c7) * 8];
            #pragma unroll
            for (int m = 0; m < 2; ++m)
                #pragma unroll
                for (int n = 0; n < 4; ++n)
                    acc[m][n] = __builtin_amdgcn_mfma_f32_16x16x32_bf16(af[m], bf[n], acc[m][n], 0, 0, 0);
        }

        __builtin_amdgcn_s_barrier();        // all waves done reading buf cur
        if (t + 2 < NT) stage(cur, (t + 2) << 6);   // restage freed buffer
    }

    if (MODE == 1) {
        if (bx < 16) {
            // fused rope + QSCALE on Q: qkvb[rowi][bx*64 + d], d = nn*16+c
            const float invf_e = __powf(10000.0f, -(float)c * (1.0f / 32.0f));
            const float invf_o = __powf(10000.0f, -(float)(c + 16) * (1.0f / 32.0f));
            #pragma unroll
            for (int m = 0; m < 2; ++m)
                #pragma unroll
                for (int r = 0; r < 4; ++r) {
                    const int rowi = m0 + wave * 32 + m * 16 + 4 * g + r;
                    const float nf = (float)(rowi & (N_ - 1));
                    float sn0, cs0, sn1, cs1;
                    __sincosf(nf * invf_e, &sn0, &cs0);
                    __sincosf(nf * invf_o, &sn1, &cs1);
                    #pragma unroll
                    for (int nn = 0; nn < 4; ++nn) {
                        const float v = acc[m][nn][r], p = acc[m][nn ^ 2][r];
                        const float rh = (nn < 2) ? -p : p;
                        const float sn = (nn & 1) ? sn1 : sn0;
                        const float cs = (nn & 1) ? cs1 : cs0;
                        ((ushort*)Cv)[(size_t)rowi * N + n0 + nn * 16 + c] =
                            f2bf((v * cs + rh * sn) * QSCALE);
                    }
                }
            return;
        }
        if (bx == 16) {
            // fused rope on Ksum: Kt[rowi][d] = k*cos + rot_half(k)*sin
            const float invf_e = __powf(10000.0f, -(float)c * (1.0f / 32.0f));
            const float invf_o = __powf(10000.0f, -(float)(c + 16) * (1.0f / 32.0f));
            #pragma unroll
            for (int m = 0; m < 2; ++m)
                #pragma unroll
                for (int r = 0; r < 4; ++r) {
                    const int rowi = m0 + wave * 32 + m * 16 + 4 * g + r;
                    const float nf = (float)(rowi & (N_ - 1));
                    float sn0, cs0, sn1, cs1;
                    __sincosf(nf * invf_e, &sn0, &cs0);
                    __sincosf(nf * invf_o, &sn1, &cs1);
                    #pragma unroll
                    for (int nn = 0; nn < 4; ++nn) {
                        const float v = acc[m][nn][r], p = acc[m][nn ^ 2][r];
                        const float rh = (nn < 2) ? -p : p;
                        const float sn = (nn & 1) ? sn1 : sn0;
                        const float cs = (nn & 1) ? cs1 : cs0;
                        Kt[(size_t)rowi * 64 + nn * 16 + c] = f2bf(v * cs + rh * sn);
                    }
                }
        } else {
            // Vsum transpose: VtT[b][d][n]
            #pragma unroll
            for (int m = 0; m < 2; ++m)
                #pragma unroll
                for (int nn = 0; nn < 4; ++nn)
                    #pragma unroll
                    for (int r = 0; r < 4; ++r) {
                        const int rowi = m0 + wave * 32 + m * 16 + 4 * g + r;
                        const int n = rowi & (N_ - 1), bb = rowi >> 11;
                        VtT[((size_t)bb * 64 + nn * 16 + c) * N_ + n] = f2bf(acc[m][nn][r]);
                    }
        }
        return;
    }

    #pragma unroll
    for (int m = 0; m < 2; ++m)
        #pragma unroll
        for (int n = 0; n < 4; ++n)
            #pragma unroll
            for (int r = 0; r < 4; ++r) {
                int rowi = m0 + wave * 32 + m * 16 + 4 * g + r;
                int coli = n0 + n * 16 + c;
                ((float*)Cv)[(size_t)rowi * N + coli] = acc[m][n][r];
            }
}

// ---------------------------------------------------------------------------
// Flash attention v17: SINGLE-PASS (no K-split, no combine kernel).
// [R10-proven: 60.3 us, best attn; unchanged]
// ---------------------------------------------------------------------------
__global__ __launch_bounds__(512) void attn17(
        const ushort* __restrict__ qkvb, const ushort* __restrict__ Kt,
        const ushort* __restrict__ VtT, ushort* __restrict__ ao) {
    const int qt = blockIdx.x & 7;
    const int h  = (blockIdx.x >> 3) & 15;
    const int b  = blockIdx.x >> 7;
    const int tid = threadIdx.x, wave = tid >> 6, lane = tid & 63;
    const int g = lane >> 4, c = lane & 15;

    __shared__ __align__(16) ushort Ksh[64 * 64];   // [j-local][d], XOR-swizzled
    __shared__ __align__(16) ushort Vsh[64 * 64];   // [d][j-local], XOR-swizzled

    const int i0 = qt * 256 + wave * 32;

    short8 qf[2][2];
    #pragma unroll
    for (int a = 0; a < 2; ++a) {
        const int row = i0 + a * 16 + c;
        const ushort* qrow = qkvb + (size_t)(b * N_ + row) * QKV_N + h * 64;
        qf[a][0] = *(const short8*)(qrow + 8 * g);
        qf[a][1] = *(const short8*)(qrow + 32 + 8 * g);
    }

    float4v o[2][4];
    #pragma unroll
    for (int a = 0; a < 2; ++a)
        #pragma unroll
        for (int f = 0; f < 4; ++f) o[a][f] = {0, 0, 0, 0};
    float ll[2] = {0.f, 0.f};

    const ushort* Kb = Kt  + (size_t)b * N_ * 64;
    const ushort* Vb = VtT + (size_t)b * 64 * N_;
    const int lr8 = lane >> 3, lq8 = lane & 7;
    const int wpos = (lq8 ^ lr8) * 8;
    const int NT = N_ / 64;

    // each wave stages 8 rows of K ([j][d]) and 8 rows of V ([d][j])
    short8 kr0 = *(const short8*)(Kb + (size_t)(wave * 8 + lr8) * 64 + lq8 * 8);
    short8 vr0 = *(const short8*)(Vb + (size_t)(wave * 8 + lr8) * N_ + lq8 * 8);

    for (int t = 0; t < NT; ++t) {
        __syncthreads();
        *(short8*)&Ksh[(wave * 8 + lr8) * 64 + wpos] = kr0;
        *(short8*)&Vsh[(wave * 8 + lr8) * 64 + wpos] = vr0;
        __syncthreads();
        if (t + 1 < NT) {
            const int jn = (t + 1) * 64;
            kr0 = *(const short8*)(Kb + (size_t)(jn + wave * 8 + lr8) * 64 + lq8 * 8);
            vr0 = *(const short8*)(Vb + (size_t)(wave * 8 + lr8) * N_ + jn + lq8 * 8);
        }

        #pragma unroll
        for (int jt4 = 0; jt4 < 4; ++jt4) {
            const int R = jt4 * 16 + c;
            short8 kf0 = *(const short8*)&Ksh[R * 64 + ((g ^ (c & 7)) * 8)];
            short8 kf1 = *(const short8*)&Ksh[R * 64 + (((g ^ 4) ^ (c & 7)) * 8)];
            short4v vf[4];
            #pragma unroll
            for (int f = 0; f < 4; ++f)
                vf[f] = *(const short4v*)&Vsh[(16 * f + c) * 64 +
                          (((jt4 * 2 + (g >> 1)) ^ (c & 7)) * 8) + (g & 1) * 4];

            #pragma unroll
            for (int a = 0; a < 2; ++a) {
                float4v st = {0, 0, 0, 0};
                st = __builtin_amdgcn_mfma_f32_16x16x32_bf16(kf0, qf[a][0], st, 0, 0, 0);
                st = __builtin_amdgcn_mfma_f32_16x16x32_bf16(kf1, qf[a][1], st, 0, 0, 0);
                float p0 = fexp2(st[0]), p1 = fexp2(st[1]);
                float p2 = fexp2(st[2]), p3 = fexp2(st[3]);
                ll[a] += (p0 + p1) + (p2 + p3);
                union { unsigned u[2]; short4v v; } pk;
                pk.u[0] = pack_bf16(p0, p1);
                pk.u[1] = pack_bf16(p2, p3);
                #pragma unroll
                for (int f = 0; f < 4; ++f)
                    o[a][f] = MFMA16K16(vf[f], pk.v, o[a][f]);
            }
        }
    }

    #pragma unroll
    for (int a = 0; a < 2; ++a) {
        float lt = ll[a];
        lt += __shfl_xor(lt, 16, 64);
        lt += __shfl_xor(lt, 32, 64);
        const float inv = 1.0f / lt;
        const int row = i0 + a * 16 + c;
        #pragma unroll
        for (int f = 0; f < 4; ++f) {
            ushort4 w;
            w.x = f2bf(o[a][f][0] * inv); w.y = f2bf(o[a][f][1] * inv);
            w.z = f2bf(o[a][f][2] * inv); w.w = f2bf(o[a][f][3] * inv);
            *(ushort4*)(ao + (size_t)(b * N_ + row) * 1024 + h * 64 + 16 * f + 4 * g) = w;
        }
    }
}

// ---------------------------------------------------------------------------
extern "C" void kernel_launch(void* const* d_in, const int* in_sizes, int n_in,
                              void* d_out, int out_size, void* d_ws, size_t ws_size,
                              hipStream_t stream) {
    const float* x     = (const float*)d_in[0];
    const float* w_q   = (const float*)d_in[1];
    const float* w_kv  = (const float*)d_in[2];
    const float* w_out = (const float*)d_in[3];
    float* out = (float*)d_out;

    const int M = B_ * N_;                               // 4096
    ushort* xb    = (ushort*)d_ws;                       // 4096*1024  (-> ao)
    ushort* wqkvT = xb    + (size_t)M * C_;              // 1152*1024
    ushort* woutT = wqkvT + (size_t)QKV_N * C_;          // 1024*1024
    ushort* qkvb  = woutT + (size_t)C_ * C_;             // 4096*1152
    ushort* Kt    = qkvb  + (size_t)M * QKV_N;           // 2*2048*64
    ushort* VtT   = Kt    + (size_t)B_ * N_ * D_;        // 2*64*2048
    ushort* ao    = xb;   // xb dead after qkv GEMM; attn writes final here

    prep<<<4624, 256, 0, stream>>>(x, w_q, w_kv, w_out, xb, wqkvT, woutT);
    gemm128p<1><<<(QKV_N / 64) * (M / 128), 256, 0, stream>>>(xb, wqkvT, qkvb, Kt, VtT, M, QKV_N, C_);
    attn17<<<B_ * H_ * (N_ / 256), 512, 0, stream>>>(qkvb, Kt, VtT, ao);
    gemm128p<2><<<(C_ / 64) * (M / 128), 256, 0, stream>>>(ao, woutT, out, nullptr, nullptr, M, C_, C_);
}

// Round 13
// 167.929 us; speedup vs baseline: 1.0704x; 1.0054x over previous
//
#include <hip/hip_runtime.h>
#include <hip/hip_bf16.h>
#include <math.h>

#define B_ 2
#define N_ 2048
#define C_ 1024
#define H_ 16
#define G_ 4
#define D_ 64
#define QKV_N 1152   // 1024 q + 64 ksum + 64 vsum

#define QSCALE 0.18033688011112042f   // 0.125 * log2(e)

using short8  = __attribute__((ext_vector_type(8))) short;
using short4v = __attribute__((ext_vector_type(4))) short;
using float4v = __attribute__((ext_vector_type(4))) float;

#if __has_builtin(__builtin_amdgcn_mfma_f32_16x16x16_bf16)
#define MFMA16K16(A, B, C) __builtin_amdgcn_mfma_f32_16x16x16_bf16(A, B, C, 0, 0, 0)
#else
#define MFMA16K16(A, B, C) __builtin_amdgcn_mfma_f32_16x16x16bf16_1k(A, B, C, 0, 0, 0)
#endif

__device__ __forceinline__ ushort f2bf(float f) {
    union { float f; unsigned u; } v; v.f = f;
    unsigned r = (v.u + 0x7FFF + ((v.u >> 16) & 1)) >> 16;  // RNE
    return (ushort)r;
}
__device__ __forceinline__ float bf2f(ushort u) {
    union { unsigned u; float f; } t; t.u = ((unsigned)u) << 16; return t.f;
}
__device__ __forceinline__ unsigned pack_bf16(float a, float b) {
#if __has_builtin(__builtin_amdgcn_cvt_pk_bf16_f32)
    auto t = __builtin_amdgcn_cvt_pk_bf16_f32(a, b);
    unsigned r; __builtin_memcpy(&r, &t, 4); return r;
#else
    return (unsigned)f2bf(a) | ((unsigned)f2bf(b) << 16);
#endif
}
__device__ __forceinline__ float fexp2(float x) {
#if __has_builtin(__builtin_amdgcn_exp2f)
    return __builtin_amdgcn_exp2f(x);
#else
    return exp2f(x);
#endif
}

// ---------------------------------------------------------------------------
// Fused prep (one launch):
//   blocks [0,4096)     : x fp32 -> bf16
//   [4096,4352)         : w_q^T   -> wqkvT rows 0..1023
//   [4352,4608)         : w_out^T -> woutT
//   [4608,4624)         : kv weight g-sum + transpose -> wqkvT rows 1024..1151
// ---------------------------------------------------------------------------
__device__ void tconv_body(const float* __restrict__ src, ushort* __restrict__ dst,
                           int K, int N, int bx, int by, float (*T)[65]) {
    const int n0 = bx * 64, k0 = by * 64;
    const int tid = threadIdx.x;
    #pragma unroll
    for (int s = 0; s < 16; ++s) {
        int idx = tid + s * 256; int r = idx >> 6, cc = idx & 63;
        T[r][cc] = src[(size_t)(k0 + r) * N + n0 + cc];
    }
    __syncthreads();
    #pragma unroll
    for (int s = 0; s < 16; ++s) {
        int idx = tid + s * 256; int r = idx >> 6, cc = idx & 63;
        dst[(size_t)(n0 + r) * K + k0 + cc] = f2bf(T[cc][r]);
    }
}

__global__ void prep(const float* __restrict__ x, const float* __restrict__ w_q,
                     const float* __restrict__ w_kv, const float* __restrict__ w_out,
                     ushort* __restrict__ xb, ushort* __restrict__ wqkvT,
                     ushort* __restrict__ woutT) {
    __shared__ float T[64][65];
    const int blk = blockIdx.x, tid = threadIdx.x;
    if (blk < 4096) {
        int i = blk * 1024 + tid * 4;
        float4 v = *(const float4*)(x + i);
        ushort4 o;
        o.x = f2bf(v.x); o.y = f2bf(v.y); o.z = f2bf(v.z); o.w = f2bf(v.w);
        *(ushort4*)(xb + i) = o;
    } else if (blk < 4352) {
        int idx = blk - 4096;
        tconv_body(w_q, wqkvT, C_, C_, idx & 15, idx >> 4, T);
    } else if (blk < 4608) {
        int idx = blk - 4352;
        tconv_body(w_out, woutT, C_, C_, idx & 15, idx >> 4, T);
    } else {
        // kv g-sum + transpose: wqkvT[1024+d][k] = sum_g w_kv[k][g*64+d],
        //                       wqkvT[1088+d][k] = sum_g w_kv[k][256+g*64+d]
        const int k0 = (blk - 4608) * 64;
        #pragma unroll
        for (int it = 0; it < 4; ++it) {
            int p = tid + it * 256;              // 1024 (kk, d-quad) pairs
            int kk = p >> 4, d4 = (p & 15) * 4;
            float ks[4] = {0, 0, 0, 0}, vs[4] = {0, 0, 0, 0};
            #pragma unroll
            for (int g = 0; g < G_; ++g) {
                float4 a = *(const float4*)(w_kv + (size_t)(k0 + kk) * 512 + g * 64 + d4);
                float4 b = *(const float4*)(w_kv + (size_t)(k0 + kk) * 512 + 256 + g * 64 + d4);
                ks[0] += a.x; ks[1] += a.y; ks[2] += a.z; ks[3] += a.w;
                vs[0] += b.x; vs[1] += b.y; vs[2] += b.z; vs[3] += b.w;
            }
            #pragma unroll
            for (int e = 0; e < 4; ++e) {
                wqkvT[(size_t)(1024 + d4 + e) * C_ + k0 + kk] = f2bf(ks[e]);
                wqkvT[(size_t)(1088 + d4 + e) * C_ + k0 + kk] = f2bf(vs[e]);
            }
        }
    }
}

// ---------------------------------------------------------------------------
// bf16 MFMA GEMM, 128x64 tile, BK=64, double-buffered LDS, counted-vmcnt
// pipeline (T4, R12), T1 XCD remap (R11), global-side XOR chunk swizzle,
// 4 waves x acc[2][4].  [R12 config — best measured total 168.8]
// MODE 1 (qkv): bx<16  -> fused rope+QSCALE on Q  -> qkvb.
//               bx==16 -> fused rope on Ksum      -> Kt[row][d].
//               bx==17 -> Vsum transpose          -> VtT[d][row].
// MODE 2 (out): f32 C write.
// ---------------------------------------------------------------------------
template <int MODE>
__global__ __launch_bounds__(256) void gemm128p(const ushort* __restrict__ A,
                                                const ushort* __restrict__ Bt,
                                                void* __restrict__ Cv,
                                                ushort* __restrict__ Kt,
                                                ushort* __restrict__ VtT,
                                                int M, int N, int K) {
    __shared__ __align__(16) ushort As[2][128 * 64];
    __shared__ __align__(16) ushort Bs[2][64 * 64];

    const int tid = threadIdx.x, wave = tid >> 6, lane = tid & 63;
    const int g = lane >> 4, c = lane & 15;

    // XCD-locality remap (T1, R11: +2us): by-chunks of 4 per XCD
    const int L = blockIdx.x;
    const int xcd = L & 7, local = L >> 3;
    const int by = xcd * 4 + (local & 3);
    const int bx = local >> 2;
    const int m0 = by * 128, n0 = bx * 64;

    const int lr = tid >> 3;                 // row within 32-row slab
    const int lq = tid & 7;                  // 16B-chunk slot within row
    const int gsw = (lq ^ (lr & 7)) * 8;     // global-side XOR chunk swizzle
    const ushort* pa = A  + (size_t)(m0 + lr) * K + gsw;
    const ushort* pb = Bt + (size_t)(n0 + lr) * K + gsw;

    auto stage = [&](int buf, int k0) {
        #pragma unroll
        for (int i = 0; i < 4; ++i)
            __builtin_amdgcn_global_load_lds(
                (const __attribute__((address_space(1))) void*)(pa + (size_t)i * 32 * K + k0),
                (__attribute__((address_space(3))) void*)&As[buf][(i * 32 + wave * 8) * 64], 16, 0, 0);
        #pragma unroll
        for (int i = 0; i < 2; ++i)
            __builtin_amdgcn_global_load_lds(
                (const __attribute__((address_space(1))) void*)(pb + (size_t)i * 32 * K + k0),
                (__attribute__((address_space(3))) void*)&Bs[buf][(i * 32 + wave * 8) * 64], 16, 0, 0);
    };

    float4v acc[2][4];
    #pragma unroll
    for (int m = 0; m < 2; ++m)
        #pragma unroll
        for (int n = 0; n < 4; ++n) acc[m][n] = {0, 0, 0, 0};

    const int NT = K >> 6;                   // 16 for K=1024
    stage(0, 0);
    stage(1, 64);                            // 12 loads in flight

    for (int t = 0; t < NT; ++t) {
        if (t + 1 < NT) {
            asm volatile("s_waitcnt vmcnt(6)" ::: "memory");   // own tile-t loads done
        } else {
            asm volatile("s_waitcnt vmcnt(0)" ::: "memory");   // final tile: drain
        }
        __builtin_amdgcn_s_barrier();        // all waves staged tile t

        const int cur = t & 1;
        #pragma unroll
        for (int kk = 0; kk < 2; ++kk) {
            const int c7 = c & 7;
            short8 af[2], bf[4];
            #pragma unroll
            for (int m = 0; m < 2; ++m)
                af[m] = *(const short8*)&As[cur][(wave * 32 + m * 16 + c) * 64 + ((kk * 4 + g) ^ c7) * 8];
            #pragma unroll
            for (int n = 0; n < 4; ++n)
                bf[n] = *(const short8*)&Bs[cur][(n * 16 + c) * 64 + ((kk * 4 + g) ^ c7) * 8];
            #pragma unroll
            for (int m = 0; m < 2; ++m)
                #pragma unroll
                for (int n = 0; n < 4; ++n)
                    acc[m][n] = __builtin_amdgcn_mfma_f32_16x16x32_bf16(af[m], bf[n], acc[m][n], 0, 0, 0);
        }

        __builtin_amdgcn_s_barrier();        // all waves done reading buf cur
        if (t + 2 < NT) stage(cur, (t + 2) << 6);   // restage freed buffer
    }

    if (MODE == 1) {
        if (bx < 16) {
            // fused rope + QSCALE on Q: qkvb[rowi][bx*64 + d], d = nn*16+c
            const float invf_e = __powf(10000.0f, -(float)c * (1.0f / 32.0f));
            const float invf_o = __powf(10000.0f, -(float)(c + 16) * (1.0f / 32.0f));
            #pragma unroll
            for (int m = 0; m < 2; ++m)
                #pragma unroll
                for (int r = 0; r < 4; ++r) {
                    const int rowi = m0 + wave * 32 + m * 16 + 4 * g + r;
                    const float nf = (float)(rowi & (N_ - 1));
                    float sn0, cs0, sn1, cs1;
                    __sincosf(nf * invf_e, &sn0, &cs0);
                    __sincosf(nf * invf_o, &sn1, &cs1);
                    #pragma unroll
                    for (int nn = 0; nn < 4; ++nn) {
                        const float v = acc[m][nn][r], p = acc[m][nn ^ 2][r];
                        const float rh = (nn < 2) ? -p : p;
                        const float sn = (nn & 1) ? sn1 : sn0;
                        const float cs = (nn & 1) ? cs1 : cs0;
                        ((ushort*)Cv)[(size_t)rowi * N + n0 + nn * 16 + c] =
                            f2bf((v * cs + rh * sn) * QSCALE);
                    }
                }
            return;
        }
        if (bx == 16) {
            // fused rope on Ksum: Kt[rowi][d] = k*cos + rot_half(k)*sin
            const float invf_e = __powf(10000.0f, -(float)c * (1.0f / 32.0f));
            const float invf_o = __powf(10000.0f, -(float)(c + 16) * (1.0f / 32.0f));
            #pragma unroll
            for (int m = 0; m < 2; ++m)
                #pragma unroll
                for (int r = 0; r < 4; ++r) {
                    const int rowi = m0 + wave * 32 + m * 16 + 4 * g + r;
                    const float nf = (float)(rowi & (N_ - 1));
                    float sn0, cs0, sn1, cs1;
                    __sincosf(nf * invf_e, &sn0, &cs0);
                    __sincosf(nf * invf_o, &sn1, &cs1);
                    #pragma unroll
                    for (int nn = 0; nn < 4; ++nn) {
                        const float v = acc[m][nn][r], p = acc[m][nn ^ 2][r];
                        const float rh = (nn < 2) ? -p : p;
                        const float sn = (nn & 1) ? sn1 : sn0;
                        const float cs = (nn & 1) ? cs1 : cs0;
                        Kt[(size_t)rowi * 64 + nn * 16 + c] = f2bf(v * cs + rh * sn);
                    }
                }
        } else {
            // Vsum transpose: VtT[b][d][n]
            #pragma unroll
            for (int m = 0; m < 2; ++m)
                #pragma unroll
                for (int nn = 0; nn < 4; ++nn)
                    #pragma unroll
                    for (int r = 0; r < 4; ++r) {
                        const int rowi = m0 + wave * 32 + m * 16 + 4 * g + r;
                        const int n = rowi & (N_ - 1), bb = rowi >> 11;
                        VtT[((size_t)bb * 64 + nn * 16 + c) * N_ + n] = f2bf(acc[m][nn][r]);
                    }
        }
        return;
    }

    #pragma unroll
    for (int m = 0; m < 2; ++m)
        #pragma unroll
        for (int n = 0; n < 4; ++n)
            #pragma unroll
            for (int r = 0; r < 4; ++r) {
                int rowi = m0 + wave * 32 + m * 16 + 4 * g + r;
                int coli = n0 + n * 16 + c;
                ((float*)Cv)[(size_t)rowi * N + coli] = acc[m][n][r];
            }
}

// ---------------------------------------------------------------------------
// Flash attention v18 = attn17 (single-pass, R10) with:
//   (1) double-buffered LDS + ONE barrier per j-tile (was 2): barrier at t
//       guarantees all waves finished compute(t-1) on buf[(t+1)&1] before
//       any wave overwrites it at t+1 -- buffer-protection barrier subsumed.
//       (attn12's dbuf regression was gload_lds-specific: its barrier
//       vmcnt(0)-drained NEXT-tile loads; reg-staged writes don't.)
//   (2) s_setprio(1) around the compute cluster (m191 regime: 8 staggered
//       waves, no lockstep).
// Barriers: 64 -> 32 per block. LDS 16KB -> 32KB (still un-binding).
// ---------------------------------------------------------------------------
__global__ __launch_bounds__(512) void attn18(
        const ushort* __restrict__ qkvb, const ushort* __restrict__ Kt,
        const ushort* __restrict__ VtT, ushort* __restrict__ ao) {
    const int qt = blockIdx.x & 7;
    const int h  = (blockIdx.x >> 3) & 15;
    const int b  = blockIdx.x >> 7;
    const int tid = threadIdx.x, wave = tid >> 6, lane = tid & 63;
    const int g = lane >> 4, c = lane & 15;

    __shared__ __align__(16) ushort Ksh[2][64 * 64];   // [j-local][d], XOR-swizzled
    __shared__ __align__(16) ushort Vsh[2][64 * 64];   // [d][j-local], XOR-swizzled

    const int i0 = qt * 256 + wave * 32;

    short8 qf[2][2];
    #pragma unroll
    for (int a = 0; a < 2; ++a) {
        const int row = i0 + a * 16 + c;
        const ushort* qrow = qkvb + (size_t)(b * N_ + row) * QKV_N + h * 64;
        qf[a][0] = *(const short8*)(qrow + 8 * g);
        qf[a][1] = *(const short8*)(qrow + 32 + 8 * g);
    }

    float4v o[2][4];
    #pragma unroll
    for (int a = 0; a < 2; ++a)
        #pragma unroll
        for (int f = 0; f < 4; ++f) o[a][f] = {0, 0, 0, 0};
    float ll[2] = {0.f, 0.f};

    const ushort* Kb = Kt  + (size_t)b * N_ * 64;
    const ushort* Vb = VtT + (size_t)b * 64 * N_;
    const int lr8 = lane >> 3, lq8 = lane & 7;
    const int wpos = (lq8 ^ lr8) * 8;
    const int NT = N_ / 64;

    // each wave stages 8 rows of K ([j][d]) and 8 rows of V ([d][j])
    short8 kr0 = *(const short8*)(Kb + (size_t)(wave * 8 + lr8) * 64 + lq8 * 8);
    short8 vr0 = *(const short8*)(Vb + (size_t)(wave * 8 + lr8) * N_ + lq8 * 8);

    for (int t = 0; t < NT; ++t) {
        const int cur = t & 1;
        *(short8*)&Ksh[cur][(wave * 8 + lr8) * 64 + wpos] = kr0;
        *(short8*)&Vsh[cur][(wave * 8 + lr8) * 64 + wpos] = vr0;
        __syncthreads();                       // single barrier per tile
        if (t + 1 < NT) {
            const int jn = (t + 1) * 64;
            kr0 = *(const short8*)(Kb + (size_t)(jn + wave * 8 + lr8) * 64 + lq8 * 8);
            vr0 = *(const short8*)(Vb + (size_t)(wave * 8 + lr8) * N_ + jn + lq8 * 8);
        }

        __builtin_amdgcn_s_setprio(1);
        #pragma unroll
        for (int jt4 = 0; jt4 < 4; ++jt4) {
            const int R = jt4 * 16 + c;
            short8 kf0 = *(const short8*)&Ksh[cur][R * 64 + ((g ^ (c & 7)) * 8)];
            short8 kf1 = *(const short8*)&Ksh[cur][R * 64 + (((g ^ 4) ^ (c & 7)) * 8)];
            short4v vf[4];
            #pragma unroll
            for (int f = 0; f < 4; ++f)
                vf[f] = *(const short4v*)&Vsh[cur][(16 * f + c) * 64 +
                          (((jt4 * 2 + (g >> 1)) ^ (c & 7)) * 8) + (g & 1) * 4];

            #pragma unroll
            for (int a = 0; a < 2; ++a) {
                float4v st = {0, 0, 0, 0};
                st = __builtin_amdgcn_mfma_f32_16x16x32_bf16(kf0, qf[a][0], st, 0, 0, 0);
                st = __builtin_amdgcn_mfma_f32_16x16x32_bf16(kf1, qf[a][1], st, 0, 0, 0);
                float p0 = fexp2(st[0]), p1 = fexp2(st[1]);
                float p2 = fexp2(st[2]), p3 = fexp2(st[3]);
                ll[a] += (p0 + p1) + (p2 + p3);
                union { unsigned u[2]; short4v v; } pk;
                pk.u[0] = pack_bf16(p0, p1);
                pk.u[1] = pack_bf16(p2, p3);
                #pragma unroll
                for (int f = 0; f < 4; ++f)
                    o[a][f] = MFMA16K16(vf[f], pk.v, o[a][f]);
            }
        }
        __builtin_amdgcn_s_setprio(0);
    }

    #pragma unroll
    for (int a = 0; a < 2; ++a) {
        float lt = ll[a];
        lt += __shfl_xor(lt, 16, 64);
        lt += __shfl_xor(lt, 32, 64);
        const float inv = 1.0f / lt;
        const int row = i0 + a * 16 + c;
        #pragma unroll
        for (int f = 0; f < 4; ++f) {
            ushort4 w;
            w.x = f2bf(o[a][f][0] * inv); w.y = f2bf(o[a][f][1] * inv);
            w.z = f2bf(o[a][f][2] * inv); w.w = f2bf(o[a][f][3] * inv);
            *(ushort4*)(ao + (size_t)(b * N_ + row) * 1024 + h * 64 + 16 * f + 4 * g) = w;
        }
    }
}

// ---------------------------------------------------------------------------
extern "C" void kernel_launch(void* const* d_in, const int* in_sizes, int n_in,
                              void* d_out, int out_size, void* d_ws, size_t ws_size,
                              hipStream_t stream) {
    const float* x     = (const float*)d_in[0];
    const float* w_q   = (const float*)d_in[1];
    const float* w_kv  = (const float*)d_in[2];
    const float* w_out = (const float*)d_in[3];
    float* out = (float*)d_out;

    const int M = B_ * N_;                               // 4096
    ushort* xb    = (ushort*)d_ws;                       // 4096*1024  (-> ao)
    ushort* wqkvT = xb    + (size_t)M * C_;              // 1152*1024
    ushort* woutT = wqkvT + (size_t)QKV_N * C_;          // 1024*1024
    ushort* qkvb  = woutT + (size_t)C_ * C_;             // 4096*1152
    ushort* Kt    = qkvb  + (size_t)M * QKV_N;           // 2*2048*64
    ushort* VtT   = Kt    + (size_t)B_ * N_ * D_;        // 2*64*2048
    ushort* ao    = xb;   // xb dead after qkv GEMM; attn writes final here

    prep<<<4624, 256, 0, stream>>>(x, w_q, w_kv, w_out, xb, wqkvT, woutT);
    gemm128p<1><<<(QKV_N / 64) * (M / 128), 256, 0, stream>>>(xb, wqkvT, qkvb, Kt, VtT, M, QKV_N, C_);
    attn18<<<B_ * H_ * (N_ / 256), 512, 0, stream>>>(qkvb, Kt, VtT, ao);
    gemm128p<2><<<(C_ / 64) * (M / 128), 256, 0, stream>>>(ao, woutT, out, nullptr, nullptr, M, C_, C_);
}